// Round 9
// baseline (270.845 us; speedup 1.0000x reference)
//
#include <hip/hip_runtime.h>
#include <hip/hip_bf16.h>

constexpr int Bc  = 1024;
constexpr int Vc  = 6890;
constexpr int Pc  = 24;
constexpr int SDc = 10;
constexpr int NJ  = Pc - 1;          // 23 rotated joints
constexpr int NC  = SDc + 9 * NJ;    // 217 coefficients
constexpr int V3  = 3 * Vc;          // 20670
constexpr int XD  = SDc + 3 * NJ;    // 79 input dims per batch

constexpr int KPAD   = 224;          // 217 padded to 7*32
constexpr int KOCT   = KPAD / 8;     // 28 k-octets
constexpr int MT     = 64;           // GEMM M tile (batch)
constexpr int NT     = 64;           // GEMM N tile (3V)
constexpr int MTILES = Bc / MT;      // 16
constexpr int NTILES = (V3 + NT - 1) / NT;  // 323
constexpr int BB2    = 16;           // batches per block in skin pass

// ---- workspace layout (byte offsets) ----
constexpr size_t JS_BYTE   = 0;                         // 792 f32
constexpr size_t COEF_BYTE = 4096;                      // coefT [NC][B] f32 = 888832 B
constexpr size_t ROT_BYTE  = COEF_BYTE + 889856;        // rotdata [B][P][12] f32 = 1179648 B
constexpr size_t WSA_BYTE  = ROT_BYTE + 1179648 + 1024; // A bf16 blocked: 16*28*64*8*2 = 458752 B
constexpr size_t WSB_BYTE  = WSA_BYTE + 458752;         // B bf16 blocked: 323*28*64*8*2 = 9261056 B
constexpr size_t WST_BYTE  = WSB_BYTE + 9261056;        // w_skinT [P][V] f32 = 661440 B

typedef __attribute__((ext_vector_type(8))) short bf16x8;
typedef __attribute__((ext_vector_type(4))) float f32x4;

__device__ inline unsigned short bf16bits(float f) {
  union { float f; unsigned u; } x; x.f = f;
  unsigned r = x.u + 0x7fffu + ((x.u >> 16) & 1u);   // RNE
  return (unsigned short)(r >> 16);
}

// ---------------- Kernel A: batch-independent joint-regressor fold ----------
__global__ __launch_bounds__(256) void lbs_prep_kernel(
    const float* __restrict__ s_mat, const float* __restrict__ v_tmpl,
    const float* __restrict__ j_reg, float* __restrict__ ws) {
  const int d = blockIdx.x;            // 0..SD   (SD => v_tmpl row)
  const int p = blockIdx.y;            // 0..P-1
  const float* src = (d < SDc) ? (s_mat + (size_t)d * V3) : v_tmpl;
  const float* jr  = j_reg + (size_t)p * Vc;
  float a0 = 0.f, a1 = 0.f, a2 = 0.f;
  for (int v = threadIdx.x; v < Vc; v += 256) {
    float w = jr[v];
    a0 += w * src[3 * v + 0];
    a1 += w * src[3 * v + 1];
    a2 += w * src[3 * v + 2];
  }
  for (int off = 32; off > 0; off >>= 1) {
    a0 += __shfl_down(a0, off);
    a1 += __shfl_down(a1, off);
    a2 += __shfl_down(a2, off);
  }
  __shared__ float red[3][4];
  const int lane = threadIdx.x & 63, wid = threadIdx.x >> 6;
  if (lane == 0) { red[0][wid] = a0; red[1][wid] = a1; red[2][wid] = a2; }
  __syncthreads();
  if (threadIdx.x == 0) {
    float r0 = red[0][0] + red[0][1] + red[0][2] + red[0][3];
    float r1 = red[1][0] + red[1][1] + red[1][2] + red[1][3];
    float r2 = red[2][0] + red[2][1] + red[2][2] + red[2][3];
    float* dst = (d < SDc) ? (ws + ((size_t)d * Pc + p) * 3)
                           : (ws + 720 + (size_t)p * 3);
    dst[0] = r0; dst[1] = r1; dst[2] = r2;
  }
}

// ---------------- Kernel B: per-batch rodrigues + kinematic chain ----------
// Fully unrolled joint loop: J[] indices become compile-time constants so
// J lives in VGPRs, not scratch (rule #20: runtime-indexed arrays -> scratch;
// round-8 profile: VGPR=36 with 72-float J => scratch, 123us at ~0% VALU).
__global__ __launch_bounds__(64) void lbs_chain_kernel(
    const float* __restrict__ x, const float* __restrict__ ws_js,
    float* __restrict__ coefT, float* __restrict__ rotdata) {
  __shared__ float js[792];
  const int t = threadIdx.x;
  for (int i = t; i < 792; i += 64) js[i] = ws_js[i];
  __syncthreads();

  const int b = blockIdx.x * 64 + t;
  const float* xb = x + (size_t)b * XD;

  float xs[SDc];
#pragma unroll
  for (int d = 0; d < SDc; ++d) xs[d] = xb[d];

  float J[Pc][3];
#pragma unroll
  for (int p = 0; p < Pc; ++p)
#pragma unroll
    for (int c = 0; c < 3; ++c) {
      float acc = js[720 + p * 3 + c];
#pragma unroll
      for (int d = 0; d < SDc; ++d) acc += xs[d] * js[(d * Pc + p) * 3 + c];
      J[p][c] = acc;
    }

#pragma unroll
  for (int d = 0; d < SDc; ++d) coefT[(size_t)d * Bc + b] = xs[d];

  float rot[3][3] = {{1, 0, 0}, {0, 1, 0}, {0, 0, 1}};
  float tr[3] = {J[0][0], J[0][1], J[0][2]};
  float* rd = rotdata + (size_t)b * Pc * 12;
  rd[0] = 1; rd[1] = 0; rd[2] = 0;
  rd[3] = 0; rd[4] = 1; rd[5] = 0;
  rd[6] = 0; rd[7] = 0; rd[8] = 1;
  rd[9] = 0; rd[10] = 0; rd[11] = 0;

#pragma unroll
  for (int i = 0; i < NJ; ++i) {
    const int n = i + 1;
    float r0 = xb[SDc + 3 * i + 0], r1 = xb[SDc + 3 * i + 1], r2 = xb[SDc + 3 * i + 2];
    float th = sqrtf(r0 * r0 + r1 * r1 + r2 * r2);
    float inv = 1.0f / fmaxf(th, 1e-8f);
    float n0 = r0 * inv, n1 = r1 * inv, n2 = r2 * inv;
    float cth = cosf(th), sth = sinf(th), omc = 1.0f - cth;
    float R[3][3];
    R[0][0] = cth + omc * n0 * n0;       R[0][1] = omc * n0 * n1 - sth * n2;  R[0][2] = omc * n0 * n2 + sth * n1;
    R[1][0] = omc * n1 * n0 + sth * n2;  R[1][1] = cth + omc * n1 * n1;       R[1][2] = omc * n1 * n2 - sth * n0;
    R[2][0] = omc * n2 * n0 - sth * n1;  R[2][1] = omc * n2 * n1 + sth * n0;  R[2][2] = cth + omc * n2 * n2;

#pragma unroll
    for (int rr = 0; rr < 3; ++rr)
#pragma unroll
      for (int cc = 0; cc < 3; ++cc)
        coefT[(size_t)(SDc + 9 * i + 3 * rr + cc) * Bc + b] =
            R[rr][cc] - (rr == cc ? 1.0f : 0.0f);

    float d0 = J[n][0] - J[i][0], d1 = J[n][1] - J[i][1], d2 = J[n][2] - J[i][2];
    float ntr[3];
#pragma unroll
    for (int r = 0; r < 3; ++r)
      ntr[r] = d0 * rot[0][r] + d1 * rot[1][r] + d2 * rot[2][r] + tr[r];

    float nr[3][3];
#pragma unroll
    for (int a = 0; a < 3; ++a)
#pragma unroll
      for (int k = 0; k < 3; ++k)
        nr[a][k] = R[0][a] * rot[0][k] + R[1][a] * rot[1][k] + R[2][a] * rot[2][k];

#pragma unroll
    for (int a = 0; a < 3; ++a)
#pragma unroll
      for (int k = 0; k < 3; ++k) rot[a][k] = nr[a][k];
    tr[0] = ntr[0]; tr[1] = ntr[1]; tr[2] = ntr[2];

    float* rdn = rd + n * 12;
#pragma unroll
    for (int a = 0; a < 3; ++a)
#pragma unroll
      for (int k = 0; k < 3; ++k) rdn[a * 3 + k] = rot[a][k];
#pragma unroll
    for (int r = 0; r < 3; ++r)
      rdn[9 + r] = tr[r] - (J[n][0] * rot[0][r] + J[n][1] * rot[1][r] + J[n][2] * rot[2][r]);
  }
}

// ---------------- packB: s_mat fp32 [K][3V] -> bf16 blocked [ntile][koct][64][8] ----
__global__ __launch_bounds__(256) void lbs_packB_kernel(
    const float* __restrict__ s_mat, unsigned short* __restrict__ wsB) {
  const int idx = blockIdx.x * 256 + threadIdx.x;     // (ntile*KOCT + ko)*64 + n_local
  if (idx >= NTILES * KOCT * 64) return;
  const int n_local = idx & 63;
  const int ko = (idx >> 6) % KOCT;
  const int ntile = idx / (64 * KOCT);
  const int n = ntile * 64 + n_local;
  unsigned short v8[8];
#pragma unroll
  for (int j = 0; j < 8; ++j) {
    const int k = ko * 8 + j;
    const float f = (k < NC && n < V3) ? s_mat[(size_t)k * V3 + n] : 0.f;
    v8[j] = bf16bits(f);
  }
  *(uint4*)&wsB[(size_t)idx * 8] = *(const uint4*)v8;
}

// ---------------- packA: coefT fp32 [K][B] -> bf16 blocked [mtile][koct][64][8] ----
__global__ __launch_bounds__(256) void lbs_packA_kernel(
    const float* __restrict__ coefT, unsigned short* __restrict__ wsA) {
  const int idx = blockIdx.x * 256 + threadIdx.x;     // (mtile*KOCT + ko)*64 + m_local
  if (idx >= MTILES * KOCT * 64) return;
  const int m_local = idx & 63;
  const int ko = (idx >> 6) % KOCT;
  const int mtile = idx / (64 * KOCT);
  const int b = mtile * 64 + m_local;
  unsigned short v8[8];
#pragma unroll
  for (int j = 0; j < 8; ++j) {
    const int k = ko * 8 + j;
    const float f = (k < NC) ? coefT[(size_t)k * Bc + b] : 0.f;
    v8[j] = bf16bits(f);
  }
  *(uint4*)&wsA[(size_t)idx * 8] = *(const uint4*)v8;
}

// ---------------- w_skin [V][P] -> w_skinT [P][V] ----------------
__global__ __launch_bounds__(256) void lbs_wskinT_kernel(
    const float* __restrict__ w_skin, float* __restrict__ w_skinT) {
  const int idx = blockIdx.x * 256 + threadIdx.x;
  if (idx >= Pc * Vc) return;
  const int p = idx / Vc, v = idx % Vc;
  w_skinT[idx] = w_skin[(size_t)v * Pc + p];
}

// ---------------- MFMA GEMM: v_posed = coef @ s_mat + v_tmpl -> d_out ------
__global__ __launch_bounds__(256) void lbs_gemm_kernel(
    const unsigned short* __restrict__ wsA, const unsigned short* __restrict__ wsB,
    const float* __restrict__ v_tmpl, float* __restrict__ out) {
  __shared__ unsigned short lA[KPAD * MT];   // 28 KB, blocked [koct][m64][k8]
  __shared__ unsigned short lB[KPAD * NT];   // 28 KB, blocked [koct][n64][k8]
  const int mtile = blockIdx.x;
  const int ntile = blockIdx.y;
  const int t = threadIdx.x;

  const unsigned short* gA = wsA + (size_t)mtile * (KPAD * MT);
  const unsigned short* gB = wsB + (size_t)ntile * (KPAD * NT);
#pragma unroll
  for (int i = 0; i < 7; ++i) {              // 7 * 256 * 16B = 28 KB
    const uint4 a = ((const uint4*)gA)[t + i * 256];
    const uint4 b = ((const uint4*)gB)[t + i * 256];
    ((uint4*)lA)[t + i * 256] = a;
    ((uint4*)lB)[t + i * 256] = b;
  }
  __syncthreads();

  const int w = t >> 6, l = t & 63;
  const int wm = (w >> 1) * 32, wn = (w & 1) * 32;
  const int lrow = l & 15, lk = l >> 4;

  f32x4 acc[2][2] = {};
#pragma unroll
  for (int kk = 0; kk < 7; ++kk) {
    const int ko = kk * 4 + lk;
    const bf16x8 a0 = *(const bf16x8*)&lA[ko * 512 + (wm + lrow) * 8];
    const bf16x8 a1 = *(const bf16x8*)&lA[ko * 512 + (wm + 16 + lrow) * 8];
    const bf16x8 b0 = *(const bf16x8*)&lB[ko * 512 + (wn + lrow) * 8];
    const bf16x8 b1 = *(const bf16x8*)&lB[ko * 512 + (wn + 16 + lrow) * 8];
    acc[0][0] = __builtin_amdgcn_mfma_f32_16x16x32_bf16(a0, b0, acc[0][0], 0, 0, 0);
    acc[0][1] = __builtin_amdgcn_mfma_f32_16x16x32_bf16(a0, b1, acc[0][1], 0, 0, 0);
    acc[1][0] = __builtin_amdgcn_mfma_f32_16x16x32_bf16(a1, b0, acc[1][0], 0, 0, 0);
    acc[1][1] = __builtin_amdgcn_mfma_f32_16x16x32_bf16(a1, b1, acc[1][1], 0, 0, 0);
  }

  const int nbase = ntile * 64 + wn;
  const int mbase = mtile * 64 + wm;
#pragma unroll
  for (int fn = 0; fn < 2; ++fn) {
    const int n = nbase + fn * 16 + lrow;
    if (n >= V3) continue;
    const float vt = v_tmpl[n];
#pragma unroll
    for (int fm = 0; fm < 2; ++fm) {
#pragma unroll
      for (int r = 0; r < 4; ++r) {
        const int m = mbase + fm * 16 + lk * 4 + r;
        out[(size_t)m * V3 + n] = acc[fm][fn][r] + vt;
      }
    }
  }
}

// ---------------- skin pass (in-place on d_out), LDS-staged rotdata --------
__global__ __launch_bounds__(256) void lbs_skin2_kernel(
    const float* __restrict__ w_skinT, const float* __restrict__ rotdata,
    float* __restrict__ out) {
  __shared__ __align__(16) float rl[BB2 * Pc * 12];   // 18432 B
  const int t = threadIdx.x;
  const int b0 = blockIdx.y * BB2;
  for (int i = t; i < BB2 * Pc * 12; i += 256)        // coalesced stage
    rl[i] = rotdata[(size_t)b0 * (Pc * 12) + i];
  __syncthreads();

  const int v = blockIdx.x * 256 + t;
  if (v >= Vc) return;
  float w[Pc];
#pragma unroll
  for (int p = 0; p < Pc; ++p) w[p] = w_skinT[(size_t)p * Vc + v];   // coalesced

  for (int bb = 0; bb < BB2; ++bb) {
    const float* rb = rl + bb * (Pc * 12);
    float4 A0 = {0, 0, 0, 0}, A1 = {0, 0, 0, 0}, A2 = {0, 0, 0, 0};
#pragma unroll
    for (int p = 0; p < Pc; ++p) {
      const float wp = w[p];
      const float4 r0 = *(const float4*)&rb[p * 12 + 0];
      const float4 r1 = *(const float4*)&rb[p * 12 + 4];
      const float4 r2 = *(const float4*)&rb[p * 12 + 8];
      A0.x += wp * r0.x; A0.y += wp * r0.y; A0.z += wp * r0.z; A0.w += wp * r0.w;
      A1.x += wp * r1.x; A1.y += wp * r1.y; A1.z += wp * r1.z; A1.w += wp * r1.w;
      A2.x += wp * r2.x; A2.y += wp * r2.y; A2.z += wp * r2.z; A2.w += wp * r2.w;
    }
    float* op = out + ((size_t)(b0 + bb) * Vc + v) * 3;
    const float vp0 = op[0], vp1 = op[1], vp2 = op[2];
    // A-layout: [0..8] rot row-major, [9..11] t_adj
    op[0] = vp0 * A0.x + vp1 * A0.w + vp2 * A1.z + A2.y;
    op[1] = vp0 * A0.y + vp1 * A1.x + vp2 * A1.w + A2.z;
    op[2] = vp0 * A0.z + vp1 * A1.y + vp2 * A2.x + A2.w;
  }
}

extern "C" void kernel_launch(void* const* d_in, const int* in_sizes, int n_in,
                              void* d_out, int out_size, void* d_ws, size_t ws_size,
                              hipStream_t stream) {
  (void)in_sizes; (void)n_in; (void)out_size; (void)ws_size;
  const float* x      = (const float*)d_in[0];
  const float* s_mat  = (const float*)d_in[1];
  const float* v_tmpl = (const float*)d_in[2];
  const float* w_skin = (const float*)d_in[3];
  const float* j_reg  = (const float*)d_in[4];
  float* out = (float*)d_out;
  char* ws = (char*)d_ws;

  float*          js      = (float*)(ws + JS_BYTE);
  float*          coefT   = (float*)(ws + COEF_BYTE);
  float*          rotdata = (float*)(ws + ROT_BYTE);
  unsigned short* wsA     = (unsigned short*)(ws + WSA_BYTE);
  unsigned short* wsB     = (unsigned short*)(ws + WSB_BYTE);
  float*          wskT    = (float*)(ws + WST_BYTE);

  lbs_prep_kernel<<<dim3(SDc + 1, Pc), 256, 0, stream>>>(s_mat, v_tmpl, j_reg, js);
  lbs_packB_kernel<<<(NTILES * KOCT * 64 + 255) / 256, 256, 0, stream>>>(s_mat, wsB);
  lbs_wskinT_kernel<<<(Pc * Vc + 255) / 256, 256, 0, stream>>>(w_skin, wskT);
  lbs_chain_kernel<<<dim3(Bc / 64), 64, 0, stream>>>(x, js, coefT, rotdata);
  lbs_packA_kernel<<<(MTILES * KOCT * 64 + 255) / 256, 256, 0, stream>>>(coefT, wsA);
  lbs_gemm_kernel<<<dim3(MTILES, NTILES), 256, 0, stream>>>(wsA, wsB, v_tmpl, out);
  lbs_skin2_kernel<<<dim3((Vc + 255) / 256, Bc / BB2), 256, 0, stream>>>(wskT, rotdata, out);
}

// Round 10
// 229.169 us; speedup vs baseline: 1.1819x; 1.1819x over previous
//
#include <hip/hip_runtime.h>
#include <hip/hip_bf16.h>

constexpr int Bc  = 1024;
constexpr int Vc  = 6890;
constexpr int Pc  = 24;
constexpr int SDc = 10;
constexpr int NJ  = Pc - 1;          // 23 rotated joints
constexpr int NC  = SDc + 9 * NJ;    // 217 coefficients
constexpr int V3  = 3 * Vc;          // 20670
constexpr int XD  = SDc + 3 * NJ;    // 79 input dims per batch

constexpr int KPAD   = 224;          // 217 padded to 7*32
constexpr int KOCT   = KPAD / 8;     // 28 k-octets
constexpr int MT     = 64;           // GEMM M tile (batch)
constexpr int NT     = 64;           // GEMM N tile (3V)
constexpr int MTILES = Bc / MT;      // 16
constexpr int NTILES = (V3 + NT - 1) / NT;  // 323
constexpr int BB2    = 8;            // batches per block in skin pass (was 16; grid-limited occupancy)

// ---- workspace layout (byte offsets) ----
constexpr size_t JS_BYTE   = 0;                         // 792 f32
constexpr size_t COEF_BYTE = 4096;                      // coefT [NC][B] f32 = 888832 B
constexpr size_t ROT_BYTE  = COEF_BYTE + 889856;        // rotdata [B][P][12] f32 = 1179648 B
constexpr size_t WSA_BYTE  = ROT_BYTE + 1179648 + 1024; // A bf16 blocked: 458752 B
constexpr size_t WSB_BYTE  = WSA_BYTE + 458752;         // B bf16 blocked: 9261056 B
constexpr size_t WST_BYTE  = WSB_BYTE + 9261056;        // w_skinT [P][V] f32 = 661440 B
constexpr size_t ROTR_BYTE = WST_BYTE + 661440;         // rotR [B][23][9] f32 = 848448 B

typedef __attribute__((ext_vector_type(8))) short bf16x8;
typedef __attribute__((ext_vector_type(4))) float f32x4;
typedef __attribute__((ext_vector_type(2))) float f32x2;

__device__ inline unsigned short bf16bits(float f) {
  union { float f; unsigned u; } x; x.f = f;
  unsigned r = x.u + 0x7fffu + ((x.u >> 16) & 1u);   // RNE
  return (unsigned short)(r >> 16);
}

// ---------------- Kernel A: batch-independent joint-regressor fold ----------
__global__ __launch_bounds__(256) void lbs_prep_kernel(
    const float* __restrict__ s_mat, const float* __restrict__ v_tmpl,
    const float* __restrict__ j_reg, float* __restrict__ ws) {
  const int d = blockIdx.x;            // 0..SD   (SD => v_tmpl row)
  const int p = blockIdx.y;            // 0..P-1
  const float* src = (d < SDc) ? (s_mat + (size_t)d * V3) : v_tmpl;
  const float* jr  = j_reg + (size_t)p * Vc;
  float a0 = 0.f, a1 = 0.f, a2 = 0.f;
  for (int v = threadIdx.x; v < Vc; v += 256) {
    float w = jr[v];
    a0 += w * src[3 * v + 0];
    a1 += w * src[3 * v + 1];
    a2 += w * src[3 * v + 2];
  }
  for (int off = 32; off > 0; off >>= 1) {
    a0 += __shfl_down(a0, off);
    a1 += __shfl_down(a1, off);
    a2 += __shfl_down(a2, off);
  }
  __shared__ float red[3][4];
  const int lane = threadIdx.x & 63, wid = threadIdx.x >> 6;
  if (lane == 0) { red[0][wid] = a0; red[1][wid] = a1; red[2][wid] = a2; }
  __syncthreads();
  if (threadIdx.x == 0) {
    float r0 = red[0][0] + red[0][1] + red[0][2] + red[0][3];
    float r1 = red[1][0] + red[1][1] + red[1][2] + red[1][3];
    float r2 = red[2][0] + red[2][1] + red[2][2] + red[2][3];
    float* dst = (d < SDc) ? (ws + ((size_t)d * Pc + p) * 3)
                           : (ws + 720 + (size_t)p * 3);
    dst[0] = r0; dst[1] = r1; dst[2] = r2;
  }
}

// ---------------- B1: (batch, joint)-parallel Rodrigues --------------------
// Writes coefT pose rows (R - I) and rotR[b][i][9] (row-major R).
__global__ __launch_bounds__(64) void lbs_rodr_kernel(
    const float* __restrict__ x, float* __restrict__ coefT,
    float* __restrict__ rotR) {
  const int b = blockIdx.x * 64 + threadIdx.x;
  const int i = blockIdx.y;
  const float* xb = x + (size_t)b * XD + SDc + 3 * i;
  const float r0 = xb[0], r1 = xb[1], r2 = xb[2];
  const float th = sqrtf(r0 * r0 + r1 * r1 + r2 * r2);
  const float inv = 1.0f / fmaxf(th, 1e-8f);
  const float n0 = r0 * inv, n1 = r1 * inv, n2 = r2 * inv;
  const float cth = cosf(th), sth = sinf(th), omc = 1.0f - cth;
  float R[9];
  R[0] = cth + omc * n0 * n0;      R[1] = omc * n0 * n1 - sth * n2; R[2] = omc * n0 * n2 + sth * n1;
  R[3] = omc * n1 * n0 + sth * n2; R[4] = cth + omc * n1 * n1;      R[5] = omc * n1 * n2 - sth * n0;
  R[6] = omc * n2 * n0 - sth * n1; R[7] = omc * n2 * n1 + sth * n0; R[8] = cth + omc * n2 * n2;
#pragma unroll
  for (int q = 0; q < 9; ++q)
    coefT[(size_t)(SDc + 9 * i + q) * Bc + b] = R[q] - ((q == 0 || q == 4 || q == 8) ? 1.0f : 0.0f);
  float* rr = rotR + ((size_t)b * NJ + i) * 9;
#pragma unroll
  for (int q = 0; q < 9; ++q) rr[q] = R[q];
}

// ---------------- B2: wave-per-batch kinematic chain scan ------------------
// Lane p computes J[p]; lane i holds R_i; 23-step scan via __shfl broadcast
// (all lanes compute rot/tr redundantly). Replaces the latency-serial chain
// kernel (r8/r9: ~100us at ~0% VALU with only 16 waves on the GPU).
__global__ __launch_bounds__(256) void lbs_chain2_kernel(
    const float* __restrict__ x, const float* __restrict__ ws_js,
    const float* __restrict__ rotR, float* __restrict__ coefT,
    float* __restrict__ rotdata) {
  __shared__ float js[792];
  __shared__ float xl[4 * 80];
  const int t = threadIdx.x;
  const int b0 = blockIdx.x * 4;
  for (int i = t; i < 792; i += 256) js[i] = ws_js[i];
  for (int j = t; j < 4 * XD; j += 256) {
    const int q = j / XD, d = j - q * XD;
    xl[q * 80 + d] = x[(size_t)(b0 + q) * XD + d];
  }
  __syncthreads();

  const int wv = t >> 6, l = t & 63;
  const int b = b0 + wv;
  const float* xw = xl + wv * 80;

  // J[p] in lane p (p<24)
  float J0 = 0.f, J1 = 0.f, J2 = 0.f;
  if (l < Pc) {
    J0 = js[720 + l * 3 + 0]; J1 = js[720 + l * 3 + 1]; J2 = js[720 + l * 3 + 2];
#pragma unroll
    for (int d = 0; d < SDc; ++d) {
      const float xd = xw[d];
      J0 += xd * js[(d * Pc + l) * 3 + 0];
      J1 += xd * js[(d * Pc + l) * 3 + 1];
      J2 += xd * js[(d * Pc + l) * 3 + 2];
    }
  }
  // x shape-rows -> coefT
  if (l < SDc) coefT[(size_t)l * Bc + b] = xw[l];

  // R_i in lane i (i<23), row-major
  float R[9];
  {
    const int ii = (l < NJ) ? l : 0;
    const float* rr = rotR + ((size_t)b * NJ + ii) * 9;
#pragma unroll
    for (int q = 0; q < 9; ++q) R[q] = rr[q];
  }

  float rot00 = 1, rot01 = 0, rot02 = 0,
        rot10 = 0, rot11 = 1, rot12 = 0,
        rot20 = 0, rot21 = 0, rot22 = 1;
  float tr0 = __shfl(J0, 0), tr1 = __shfl(J1, 0), tr2 = __shfl(J2, 0);
  (void)tr0; (void)tr1; (void)tr2;

  // node 0: rot = I, t_adj = 0
  if (l < 12) rotdata[((size_t)b * Pc + 0) * 12 + l] = (l == 0 || l == 4 || l == 8) ? 1.f : 0.f;

#pragma unroll
  for (int i = 0; i < NJ; ++i) {
    const int n = i + 1;
    float Rb[9];
#pragma unroll
    for (int q = 0; q < 9; ++q) Rb[q] = __shfl(R[q], i);
    const float Jn0 = __shfl(J0, n), Jn1 = __shfl(J1, n), Jn2 = __shfl(J2, n);
    const float Ji0 = __shfl(J0, i), Ji1 = __shfl(J1, i), Ji2 = __shfl(J2, i);
    const float d0 = Jn0 - Ji0, d1 = Jn1 - Ji1, d2 = Jn2 - Ji2;
    // trans_n = (J[n]-J[i]) @ rot_parent + tr   (parent rot, pre-update)
    const float ntr0 = d0 * rot00 + d1 * rot10 + d2 * rot20 + tr0;
    const float ntr1 = d0 * rot01 + d1 * rot11 + d2 * rot21 + tr1;
    const float ntr2 = d0 * rot02 + d1 * rot12 + d2 * rot22 + tr2;
    // rot_n[a][k] = sum_j R[j][a] * rot_parent[j][k]
    const float nr00 = Rb[0] * rot00 + Rb[3] * rot10 + Rb[6] * rot20;
    const float nr01 = Rb[0] * rot01 + Rb[3] * rot11 + Rb[6] * rot21;
    const float nr02 = Rb[0] * rot02 + Rb[3] * rot12 + Rb[6] * rot22;
    const float nr10 = Rb[1] * rot00 + Rb[4] * rot10 + Rb[7] * rot20;
    const float nr11 = Rb[1] * rot01 + Rb[4] * rot11 + Rb[7] * rot21;
    const float nr12 = Rb[1] * rot02 + Rb[4] * rot12 + Rb[7] * rot22;
    const float nr20 = Rb[2] * rot00 + Rb[5] * rot10 + Rb[8] * rot20;
    const float nr21 = Rb[2] * rot01 + Rb[5] * rot11 + Rb[8] * rot21;
    const float nr22 = Rb[2] * rot02 + Rb[5] * rot12 + Rb[8] * rot22;
    rot00 = nr00; rot01 = nr01; rot02 = nr02;
    rot10 = nr10; rot11 = nr11; rot12 = nr12;
    rot20 = nr20; rot21 = nr21; rot22 = nr22;
    tr0 = ntr0; tr1 = ntr1; tr2 = ntr2;
    // t_adj = tr - J[n] @ rot_n
    const float ta0 = tr0 - (Jn0 * rot00 + Jn1 * rot10 + Jn2 * rot20);
    const float ta1 = tr1 - (Jn0 * rot01 + Jn1 * rot11 + Jn2 * rot21);
    const float ta2 = tr2 - (Jn0 * rot02 + Jn1 * rot12 + Jn2 * rot22);
    if (l == 0) {
      float* rdn = rotdata + ((size_t)b * Pc + n) * 12;
      rdn[0] = rot00; rdn[1] = rot01; rdn[2] = rot02;
      rdn[3] = rot10; rdn[4] = rot11; rdn[5] = rot12;
      rdn[6] = rot20; rdn[7] = rot21; rdn[8] = rot22;
      rdn[9] = ta0; rdn[10] = ta1; rdn[11] = ta2;
    }
  }
}

// ---------------- packB: s_mat fp32 [K][3V] -> bf16 blocked [ntile][koct][64][8] ----
__global__ __launch_bounds__(256) void lbs_packB_kernel(
    const float* __restrict__ s_mat, unsigned short* __restrict__ wsB) {
  const int idx = blockIdx.x * 256 + threadIdx.x;
  if (idx >= NTILES * KOCT * 64) return;
  const int n_local = idx & 63;
  const int ko = (idx >> 6) % KOCT;
  const int ntile = idx / (64 * KOCT);
  const int n = ntile * 64 + n_local;
  unsigned short v8[8];
#pragma unroll
  for (int j = 0; j < 8; ++j) {
    const int k = ko * 8 + j;
    const float f = (k < NC && n < V3) ? s_mat[(size_t)k * V3 + n] : 0.f;
    v8[j] = bf16bits(f);
  }
  *(uint4*)&wsB[(size_t)idx * 8] = *(const uint4*)v8;
}

// ---------------- packA: coefT fp32 [K][B] -> bf16 blocked [mtile][koct][64][8] ----
__global__ __launch_bounds__(256) void lbs_packA_kernel(
    const float* __restrict__ coefT, unsigned short* __restrict__ wsA) {
  const int idx = blockIdx.x * 256 + threadIdx.x;
  if (idx >= MTILES * KOCT * 64) return;
  const int m_local = idx & 63;
  const int ko = (idx >> 6) % KOCT;
  const int mtile = idx / (64 * KOCT);
  const int b = mtile * 64 + m_local;
  unsigned short v8[8];
#pragma unroll
  for (int j = 0; j < 8; ++j) {
    const int k = ko * 8 + j;
    const float f = (k < NC) ? coefT[(size_t)k * Bc + b] : 0.f;
    v8[j] = bf16bits(f);
  }
  *(uint4*)&wsA[(size_t)idx * 8] = *(const uint4*)v8;
}

// ---------------- w_skin [V][P] -> w_skinT [P][V] ----------------
__global__ __launch_bounds__(256) void lbs_wskinT_kernel(
    const float* __restrict__ w_skin, float* __restrict__ w_skinT) {
  const int idx = blockIdx.x * 256 + threadIdx.x;
  if (idx >= Pc * Vc) return;
  const int p = idx / Vc, v = idx % Vc;
  w_skinT[idx] = w_skin[(size_t)v * Pc + p];
}

// ---------------- MFMA GEMM: v_posed = coef @ s_mat + v_tmpl -> d_out ------
__global__ __launch_bounds__(256) void lbs_gemm_kernel(
    const unsigned short* __restrict__ wsA, const unsigned short* __restrict__ wsB,
    const float* __restrict__ v_tmpl, float* __restrict__ out) {
  __shared__ unsigned short lA[KPAD * MT];   // 28 KB
  __shared__ unsigned short lB[KPAD * NT];   // 28 KB
  const int mtile = blockIdx.x;
  const int ntile = blockIdx.y;
  const int t = threadIdx.x;

  const unsigned short* gA = wsA + (size_t)mtile * (KPAD * MT);
  const unsigned short* gB = wsB + (size_t)ntile * (KPAD * NT);
#pragma unroll
  for (int i = 0; i < 7; ++i) {
    const uint4 a = ((const uint4*)gA)[t + i * 256];
    const uint4 b = ((const uint4*)gB)[t + i * 256];
    ((uint4*)lA)[t + i * 256] = a;
    ((uint4*)lB)[t + i * 256] = b;
  }
  __syncthreads();

  const int w = t >> 6, l = t & 63;
  const int wm = (w >> 1) * 32, wn = (w & 1) * 32;
  const int lrow = l & 15, lk = l >> 4;

  f32x4 acc[2][2] = {};
#pragma unroll
  for (int kk = 0; kk < 7; ++kk) {
    const int ko = kk * 4 + lk;
    const bf16x8 a0 = *(const bf16x8*)&lA[ko * 512 + (wm + lrow) * 8];
    const bf16x8 a1 = *(const bf16x8*)&lA[ko * 512 + (wm + 16 + lrow) * 8];
    const bf16x8 b0 = *(const bf16x8*)&lB[ko * 512 + (wn + lrow) * 8];
    const bf16x8 b1 = *(const bf16x8*)&lB[ko * 512 + (wn + 16 + lrow) * 8];
    acc[0][0] = __builtin_amdgcn_mfma_f32_16x16x32_bf16(a0, b0, acc[0][0], 0, 0, 0);
    acc[0][1] = __builtin_amdgcn_mfma_f32_16x16x32_bf16(a0, b1, acc[0][1], 0, 0, 0);
    acc[1][0] = __builtin_amdgcn_mfma_f32_16x16x32_bf16(a1, b0, acc[1][0], 0, 0, 0);
    acc[1][1] = __builtin_amdgcn_mfma_f32_16x16x32_bf16(a1, b1, acc[1][1], 0, 0, 0);
  }

  const int nbase = ntile * 64 + wn;
  const int mbase = mtile * 64 + wm;
#pragma unroll
  for (int fn = 0; fn < 2; ++fn) {
    const int n = nbase + fn * 16 + lrow;
    if (n >= V3) continue;
    const float vt = v_tmpl[n];
#pragma unroll
    for (int fm = 0; fm < 2; ++fm) {
#pragma unroll
      for (int r = 0; r < 4; ++r) {
        const int m = mbase + fm * 16 + lk * 4 + r;
        out[(size_t)m * V3 + n] = acc[fm][fn][r] + vt;
      }
    }
  }
}

// ---------------- skin pass (in-place on d_out), LDS rotdata, packed f32 ---
__global__ __launch_bounds__(256) void lbs_skin2_kernel(
    const float* __restrict__ w_skinT, const float* __restrict__ rotdata,
    float* __restrict__ out) {
  __shared__ __align__(16) float rl[BB2 * Pc * 12];   // 9216 B
  const int t = threadIdx.x;
  const int b0 = blockIdx.y * BB2;
  for (int i = t; i < BB2 * Pc * 12; i += 256)
    rl[i] = rotdata[(size_t)b0 * (Pc * 12) + i];
  __syncthreads();

  const int v = blockIdx.x * 256 + t;
  if (v >= Vc) return;
  float w[Pc];
#pragma unroll
  for (int p = 0; p < Pc; ++p) w[p] = w_skinT[(size_t)p * Vc + v];

  for (int bb = 0; bb < BB2; ++bb) {
    const float* rb = rl + bb * (Pc * 12);
    f32x2 a0 = {0.f, 0.f}, a1 = {0.f, 0.f}, a2 = {0.f, 0.f},
          a3 = {0.f, 0.f}, a4 = {0.f, 0.f}, a5 = {0.f, 0.f};
#pragma unroll
    for (int p = 0; p < Pc; ++p) {
      const f32x4 r0 = *(const f32x4*)&rb[p * 12 + 0];
      const f32x4 r1 = *(const f32x4*)&rb[p * 12 + 4];
      const f32x4 r2 = *(const f32x4*)&rb[p * 12 + 8];
      const float wp = w[p];
      const f32x2 wp2 = {wp, wp};
      f32x2 q;
      q.x = r0.x; q.y = r0.y; a0 += wp2 * q;
      q.x = r0.z; q.y = r0.w; a1 += wp2 * q;
      q.x = r1.x; q.y = r1.y; a2 += wp2 * q;
      q.x = r1.z; q.y = r1.w; a3 += wp2 * q;
      q.x = r2.x; q.y = r2.y; a4 += wp2 * q;
      q.x = r2.z; q.y = r2.w; a5 += wp2 * q;
    }
    // A[12] = {a0.x,a0.y, a1.x,a1.y, a2.x,a2.y, a3.x,a3.y, a4.x,a4.y, a5.x,a5.y}
    float* op = out + ((size_t)(b0 + bb) * Vc + v) * 3;
    const float vp0 = op[0], vp1 = op[1], vp2 = op[2];
    op[0] = vp0 * a0.x + vp1 * a1.y + vp2 * a3.x + a4.y;
    op[1] = vp0 * a0.y + vp1 * a2.x + vp2 * a3.y + a5.x;
    op[2] = vp0 * a1.x + vp1 * a2.y + vp2 * a4.x + a5.y;
  }
}

extern "C" void kernel_launch(void* const* d_in, const int* in_sizes, int n_in,
                              void* d_out, int out_size, void* d_ws, size_t ws_size,
                              hipStream_t stream) {
  (void)in_sizes; (void)n_in; (void)out_size; (void)ws_size;
  const float* x      = (const float*)d_in[0];
  const float* s_mat  = (const float*)d_in[1];
  const float* v_tmpl = (const float*)d_in[2];
  const float* w_skin = (const float*)d_in[3];
  const float* j_reg  = (const float*)d_in[4];
  float* out = (float*)d_out;
  char* ws = (char*)d_ws;

  float*          js      = (float*)(ws + JS_BYTE);
  float*          coefT   = (float*)(ws + COEF_BYTE);
  float*          rotdata = (float*)(ws + ROT_BYTE);
  unsigned short* wsA     = (unsigned short*)(ws + WSA_BYTE);
  unsigned short* wsB     = (unsigned short*)(ws + WSB_BYTE);
  float*          wskT    = (float*)(ws + WST_BYTE);
  float*          rotR    = (float*)(ws + ROTR_BYTE);

  lbs_prep_kernel<<<dim3(SDc + 1, Pc), 256, 0, stream>>>(s_mat, v_tmpl, j_reg, js);
  lbs_packB_kernel<<<(NTILES * KOCT * 64 + 255) / 256, 256, 0, stream>>>(s_mat, wsB);
  lbs_wskinT_kernel<<<(Pc * Vc + 255) / 256, 256, 0, stream>>>(w_skin, wskT);
  lbs_rodr_kernel<<<dim3(Bc / 64, NJ), 64, 0, stream>>>(x, coefT, rotR);
  lbs_chain2_kernel<<<dim3(Bc / 4), 256, 0, stream>>>(x, js, rotR, coefT, rotdata);
  lbs_packA_kernel<<<(MTILES * KOCT * 64 + 255) / 256, 256, 0, stream>>>(coefT, wsA);
  lbs_gemm_kernel<<<dim3(MTILES, NTILES), 256, 0, stream>>>(wsA, wsB, v_tmpl, out);
  lbs_skin2_kernel<<<dim3((Vc + 255) / 256, Bc / BB2), 256, 0, stream>>>(wskT, rotdata, out);
}

// Round 11
// 197.385 us; speedup vs baseline: 1.3722x; 1.1610x over previous
//
#include <hip/hip_runtime.h>
#include <hip/hip_bf16.h>

constexpr int Bc  = 1024;
constexpr int Vc  = 6890;
constexpr int Pc  = 24;
constexpr int SDc = 10;
constexpr int NJ  = Pc - 1;          // 23 rotated joints
constexpr int NC  = SDc + 9 * NJ;    // 217 coefficients
constexpr int V3  = 3 * Vc;          // 20670
constexpr int XD  = SDc + 3 * NJ;    // 79 input dims per batch

constexpr int KPAD   = 224;          // 217 padded to 7*32
constexpr int KOCT   = KPAD / 8;     // 28 k-octets
constexpr int MT     = 64;           // GEMM M tile (batch)
constexpr int NT     = 48;           // GEMM N tile: LCM(16,3) -> 16 whole vertices
constexpr int MTILES = Bc / MT;      // 16
constexpr int VTILES = (V3 + NT - 1) / NT;  // 431 (16-vertex tiles)

// ---- workspace layout (byte offsets); peak 13291520 <= 13.3MB proven in r10 ----
constexpr size_t JS_BYTE   = 0;                          // 792 f32
constexpr size_t COEF_BYTE = 4096;                       // coefT [NC][B] f32
constexpr size_t ROT_BYTE  = COEF_BYTE + 889856;         // rotdata [B][24][12] f32
constexpr size_t WSA_BYTE  = ROT_BYTE + 1179648 + 1024;  // A bf16 blocked 458752 B
constexpr size_t WSB_BYTE  = WSA_BYTE + 458752;          // B bf16 48-col blocked 9268224 B
constexpr size_t ROTR_BYTE = WSB_BYTE + 9268224;         // rotR [B][23][9] f32 (dead after chain2)
constexpr size_t TP_BYTE   = ROTR_BYTE;                  // T_pack bf16 [B][4][16][8] 1048576 B (aliases dead rotR)
constexpr size_t WP_BYTE   = TP_BYTE + 1048576;          // w_pack bf16 [431][4][16][8] 441344 B

typedef __attribute__((ext_vector_type(8))) short bf16x8;
typedef __attribute__((ext_vector_type(4))) float f32x4;

__device__ inline unsigned short bf16bits(float f) {
  union { float f; unsigned u; } x; x.f = f;
  unsigned r = x.u + 0x7fffu + ((x.u >> 16) & 1u);   // RNE
  return (unsigned short)(r >> 16);
}

// ---------------- Kernel A: batch-independent joint-regressor fold ----------
__global__ __launch_bounds__(256) void lbs_prep_kernel(
    const float* __restrict__ s_mat, const float* __restrict__ v_tmpl,
    const float* __restrict__ j_reg, float* __restrict__ ws) {
  const int d = blockIdx.x;            // 0..SD   (SD => v_tmpl row)
  const int p = blockIdx.y;            // 0..P-1
  const float* src = (d < SDc) ? (s_mat + (size_t)d * V3) : v_tmpl;
  const float* jr  = j_reg + (size_t)p * Vc;
  float a0 = 0.f, a1 = 0.f, a2 = 0.f;
  for (int v = threadIdx.x; v < Vc; v += 256) {
    float w = jr[v];
    a0 += w * src[3 * v + 0];
    a1 += w * src[3 * v + 1];
    a2 += w * src[3 * v + 2];
  }
  for (int off = 32; off > 0; off >>= 1) {
    a0 += __shfl_down(a0, off);
    a1 += __shfl_down(a1, off);
    a2 += __shfl_down(a2, off);
  }
  __shared__ float red[3][4];
  const int lane = threadIdx.x & 63, wid = threadIdx.x >> 6;
  if (lane == 0) { red[0][wid] = a0; red[1][wid] = a1; red[2][wid] = a2; }
  __syncthreads();
  if (threadIdx.x == 0) {
    float r0 = red[0][0] + red[0][1] + red[0][2] + red[0][3];
    float r1 = red[1][0] + red[1][1] + red[1][2] + red[1][3];
    float r2 = red[2][0] + red[2][1] + red[2][2] + red[2][3];
    float* dst = (d < SDc) ? (ws + ((size_t)d * Pc + p) * 3)
                           : (ws + 720 + (size_t)p * 3);
    dst[0] = r0; dst[1] = r1; dst[2] = r2;
  }
}

// ---------------- B1: (batch, joint)-parallel Rodrigues --------------------
__global__ __launch_bounds__(64) void lbs_rodr_kernel(
    const float* __restrict__ x, float* __restrict__ coefT,
    float* __restrict__ rotR) {
  const int b = blockIdx.x * 64 + threadIdx.x;
  const int i = blockIdx.y;
  const float* xb = x + (size_t)b * XD + SDc + 3 * i;
  const float r0 = xb[0], r1 = xb[1], r2 = xb[2];
  const float th = sqrtf(r0 * r0 + r1 * r1 + r2 * r2);
  const float inv = 1.0f / fmaxf(th, 1e-8f);
  const float n0 = r0 * inv, n1 = r1 * inv, n2 = r2 * inv;
  const float cth = cosf(th), sth = sinf(th), omc = 1.0f - cth;
  float R[9];
  R[0] = cth + omc * n0 * n0;      R[1] = omc * n0 * n1 - sth * n2; R[2] = omc * n0 * n2 + sth * n1;
  R[3] = omc * n1 * n0 + sth * n2; R[4] = cth + omc * n1 * n1;      R[5] = omc * n1 * n2 - sth * n0;
  R[6] = omc * n2 * n0 - sth * n1; R[7] = omc * n2 * n1 + sth * n0; R[8] = cth + omc * n2 * n2;
#pragma unroll
  for (int q = 0; q < 9; ++q)
    coefT[(size_t)(SDc + 9 * i + q) * Bc + b] = R[q] - ((q == 0 || q == 4 || q == 8) ? 1.0f : 0.0f);
  float* rr = rotR + ((size_t)b * NJ + i) * 9;
#pragma unroll
  for (int q = 0; q < 9; ++q) rr[q] = R[q];
}

// ---------------- B2: wave-per-batch kinematic chain scan ------------------
__global__ __launch_bounds__(256) void lbs_chain2_kernel(
    const float* __restrict__ x, const float* __restrict__ ws_js,
    const float* __restrict__ rotR, float* __restrict__ coefT,
    float* __restrict__ rotdata) {
  __shared__ float js[792];
  __shared__ float xl[4 * 80];
  const int t = threadIdx.x;
  const int b0 = blockIdx.x * 4;
  for (int i = t; i < 792; i += 256) js[i] = ws_js[i];
  for (int j = t; j < 4 * XD; j += 256) {
    const int q = j / XD, d = j - q * XD;
    xl[q * 80 + d] = x[(size_t)(b0 + q) * XD + d];
  }
  __syncthreads();

  const int wv = t >> 6, l = t & 63;
  const int b = b0 + wv;
  const float* xw = xl + wv * 80;

  float J0 = 0.f, J1 = 0.f, J2 = 0.f;
  if (l < Pc) {
    J0 = js[720 + l * 3 + 0]; J1 = js[720 + l * 3 + 1]; J2 = js[720 + l * 3 + 2];
#pragma unroll
    for (int d = 0; d < SDc; ++d) {
      const float xd = xw[d];
      J0 += xd * js[(d * Pc + l) * 3 + 0];
      J1 += xd * js[(d * Pc + l) * 3 + 1];
      J2 += xd * js[(d * Pc + l) * 3 + 2];
    }
  }
  if (l < SDc) coefT[(size_t)l * Bc + b] = xw[l];

  float R[9];
  {
    const int ii = (l < NJ) ? l : 0;
    const float* rr = rotR + ((size_t)b * NJ + ii) * 9;
#pragma unroll
    for (int q = 0; q < 9; ++q) R[q] = rr[q];
  }

  float rot00 = 1, rot01 = 0, rot02 = 0,
        rot10 = 0, rot11 = 1, rot12 = 0,
        rot20 = 0, rot21 = 0, rot22 = 1;
  float tr0 = __shfl(J0, 0), tr1 = __shfl(J1, 0), tr2 = __shfl(J2, 0);

  if (l < 12) rotdata[((size_t)b * Pc + 0) * 12 + l] = (l == 0 || l == 4 || l == 8) ? 1.f : 0.f;

#pragma unroll
  for (int i = 0; i < NJ; ++i) {
    const int n = i + 1;
    float Rb[9];
#pragma unroll
    for (int q = 0; q < 9; ++q) Rb[q] = __shfl(R[q], i);
    const float Jn0 = __shfl(J0, n), Jn1 = __shfl(J1, n), Jn2 = __shfl(J2, n);
    const float Ji0 = __shfl(J0, i), Ji1 = __shfl(J1, i), Ji2 = __shfl(J2, i);
    const float d0 = Jn0 - Ji0, d1 = Jn1 - Ji1, d2 = Jn2 - Ji2;
    const float ntr0 = d0 * rot00 + d1 * rot10 + d2 * rot20 + tr0;
    const float ntr1 = d0 * rot01 + d1 * rot11 + d2 * rot21 + tr1;
    const float ntr2 = d0 * rot02 + d1 * rot12 + d2 * rot22 + tr2;
    const float nr00 = Rb[0] * rot00 + Rb[3] * rot10 + Rb[6] * rot20;
    const float nr01 = Rb[0] * rot01 + Rb[3] * rot11 + Rb[6] * rot21;
    const float nr02 = Rb[0] * rot02 + Rb[3] * rot12 + Rb[6] * rot22;
    const float nr10 = Rb[1] * rot00 + Rb[4] * rot10 + Rb[7] * rot20;
    const float nr11 = Rb[1] * rot01 + Rb[4] * rot11 + Rb[7] * rot21;
    const float nr12 = Rb[1] * rot02 + Rb[4] * rot12 + Rb[7] * rot22;
    const float nr20 = Rb[2] * rot00 + Rb[5] * rot10 + Rb[8] * rot20;
    const float nr21 = Rb[2] * rot01 + Rb[5] * rot11 + Rb[8] * rot21;
    const float nr22 = Rb[2] * rot02 + Rb[5] * rot12 + Rb[8] * rot22;
    rot00 = nr00; rot01 = nr01; rot02 = nr02;
    rot10 = nr10; rot11 = nr11; rot12 = nr12;
    rot20 = nr20; rot21 = nr21; rot22 = nr22;
    tr0 = ntr0; tr1 = ntr1; tr2 = ntr2;
    const float ta0 = tr0 - (Jn0 * rot00 + Jn1 * rot10 + Jn2 * rot20);
    const float ta1 = tr1 - (Jn0 * rot01 + Jn1 * rot11 + Jn2 * rot21);
    const float ta2 = tr2 - (Jn0 * rot02 + Jn1 * rot12 + Jn2 * rot22);
    if (l == 0) {
      float* rdn = rotdata + ((size_t)b * Pc + n) * 12;
      rdn[0] = rot00; rdn[1] = rot01; rdn[2] = rot02;
      rdn[3] = rot10; rdn[4] = rot11; rdn[5] = rot12;
      rdn[6] = rot20; rdn[7] = rot21; rdn[8] = rot22;
      rdn[9] = ta0; rdn[10] = ta1; rdn[11] = ta2;
    }
  }
}

// ---------------- packB48: s_mat -> bf16 blocked [vtile][koct][48][8] -------
__global__ __launch_bounds__(256) void lbs_packB48_kernel(
    const float* __restrict__ s_mat, unsigned short* __restrict__ wsB) {
  const int idx = blockIdx.x * 256 + threadIdx.x;   // (vt*KOCT + ko)*48 + col
  if (idx >= VTILES * KOCT * 48) return;
  const int col = idx % 48;
  const int ko  = (idx / 48) % KOCT;
  const int vt  = idx / (48 * KOCT);
  const int n = vt * 48 + col;
  unsigned short v8[8];
#pragma unroll
  for (int j = 0; j < 8; ++j) {
    const int k = ko * 8 + j;
    const float f = (k < NC && n < V3) ? s_mat[(size_t)k * V3 + n] : 0.f;
    v8[j] = bf16bits(f);
  }
  *(uint4*)&wsB[(size_t)idx * 8] = *(const uint4*)v8;
}

// ---------------- packA: coefT -> bf16 blocked [mtile][koct][64][8] ---------
__global__ __launch_bounds__(256) void lbs_packA_kernel(
    const float* __restrict__ coefT, unsigned short* __restrict__ wsA) {
  const int idx = blockIdx.x * 256 + threadIdx.x;
  if (idx >= MTILES * KOCT * 64) return;
  const int m_local = idx & 63;
  const int ko = (idx >> 6) % KOCT;
  const int mtile = idx / (64 * KOCT);
  const int b = mtile * 64 + m_local;
  unsigned short v8[8];
#pragma unroll
  for (int j = 0; j < 8; ++j) {
    const int k = ko * 8 + j;
    const float f = (k < NC) ? coefT[(size_t)k * Bc + b] : 0.f;
    v8[j] = bf16bits(f);
  }
  *(uint4*)&wsA[(size_t)idx * 8] = *(const uint4*)v8;
}

// ---------------- tpack: rotdata -> bf16 B-operand layout [b][ko4][c16][j8] -
__global__ __launch_bounds__(256) void lbs_tpack_kernel(
    const float* __restrict__ rotdata, unsigned short* __restrict__ tp) {
  const int idx = blockIdx.x * 256 + threadIdx.x;   // (b*4 + ko)*16 + c
  if (idx >= Bc * 4 * 16) return;
  const int c  = idx & 15;
  const int ko = (idx >> 4) & 3;
  const int b  = idx >> 6;
  unsigned short v8[8];
#pragma unroll
  for (int j = 0; j < 8; ++j) {
    const int p = ko * 8 + j;
    const float f = (p < Pc && c < 12) ? rotdata[((size_t)b * Pc + p) * 12 + c] : 0.f;
    v8[j] = bf16bits(f);
  }
  *(uint4*)&tp[(size_t)idx * 8] = *(const uint4*)v8;
}

// ---------------- wpack: w_skin -> bf16 A-operand layout [vt][ko4][v16][j8] -
__global__ __launch_bounds__(256) void lbs_wpack_kernel(
    const float* __restrict__ w_skin, unsigned short* __restrict__ wp) {
  const int idx = blockIdx.x * 256 + threadIdx.x;   // (vt*4 + ko)*16 + i
  if (idx >= VTILES * 4 * 16) return;
  const int i  = idx & 15;
  const int ko = (idx >> 4) & 3;
  const int vt = idx >> 6;
  const int v = vt * 16 + i;
  unsigned short v8[8];
#pragma unroll
  for (int j = 0; j < 8; ++j) {
    const int p = ko * 8 + j;
    const float f = (p < Pc && v < Vc) ? w_skin[(size_t)v * Pc + p] : 0.f;
    v8[j] = bf16bits(f);
  }
  *(uint4*)&wp[(size_t)idx * 8] = *(const uint4*)v8;
}

// ---------------- fused: blendshape-GEMM + MFMA skinning -> out (write-only)
// Phase1: 64b x 48col MFMA GEMM (v_posed in regs -> LDS).
// Phase2: per 16-b chunk: blend A = w @ T via MFMA (K=24pad32, N=12pad16),
//         LDS bounce, per-thread apply, single coalesced out write.
__global__ __launch_bounds__(256) void lbs_fused_kernel(
    const unsigned short* __restrict__ wsA, const unsigned short* __restrict__ wsB,
    const unsigned short* __restrict__ tpack, const unsigned short* __restrict__ wpack,
    const float* __restrict__ v_tmpl, float* __restrict__ out) {
  __shared__ __align__(16) unsigned char lds[50176];   // 49 KB
  unsigned short* lA = (unsigned short*)lds;                    // [ko][64][8] 28672 B
  unsigned short* lB = (unsigned short*)(lds + 28672);          // [ko][48][8] 21504 B
  float* vposed = (float*)lds;                                  // [64][48] 12288 B (phase2)
  float* Abuf   = (float*)(lds + 12288);                        // [16b][16v][12] 12288 B (phase2)

  const int mtile = blockIdx.x;
  const int vt    = blockIdx.y;
  const int t = threadIdx.x;
  const int w = t >> 6, l = t & 63;
  const int lrow = l & 15, lk = l >> 4;

  // ---- stage A/B tiles ----
  const unsigned short* gA = wsA + (size_t)mtile * (KPAD * MT);
  const unsigned short* gB = wsB + (size_t)vt * (KOCT * 48 * 8);
#pragma unroll
  for (int i = 0; i < 7; ++i)                       // 1792 uint4
    ((uint4*)lA)[t + i * 256] = ((const uint4*)gA)[t + i * 256];
#pragma unroll
  for (int i = 0; i < 6; ++i) {                     // 1344 uint4
    const int idx = t + i * 256;
    if (idx < 1344) ((uint4*)lB)[idx] = ((const uint4*)gB)[idx];
  }
  __syncthreads();

  // ---- phase 1: main GEMM, wave w owns m-rows [w*16, w*16+16) x all 48 cols
  f32x4 acc[3] = {};
#pragma unroll
  for (int kk = 0; kk < 7; ++kk) {
    const int ko = kk * 4 + lk;
    const bf16x8 a = *(const bf16x8*)&lA[(ko * 64 + w * 16 + lrow) * 8];
#pragma unroll
    for (int f = 0; f < 3; ++f) {
      const bf16x8 bf = *(const bf16x8*)&lB[(ko * 48 + f * 16 + lrow) * 8];
      acc[f] = __builtin_amdgcn_mfma_f32_16x16x32_bf16(a, bf, acc[f], 0, 0, 0);
    }
  }

  // w-operand fragment for blend MFMA (global, coalesced: lane l -> +l*8 shorts)
  const bf16x8 wfrag = *(const bf16x8*)(wpack + (size_t)vt * 512 + l * 8);

  __syncthreads();   // done reading lA/lB; reuse LDS

  // ---- v_posed (+v_tmpl) -> LDS [m 64][col 48]
#pragma unroll
  for (int f = 0; f < 3; ++f) {
    const int ng = vt * 48 + f * 16 + lrow;
    const float vtv = (ng < V3) ? v_tmpl[ng] : 0.f;
#pragma unroll
    for (int r = 0; r < 4; ++r)
      vposed[(w * 16 + lk * 4 + r) * 48 + f * 16 + lrow] = acc[f][r] + vtv;
  }
  __syncthreads();

  // ---- phase 2: 4 chunks of 16 batches
  const int vg = vt * 16 + (t & 15);     // apply-vertex per thread
  for (int c4 = 0; c4 < 4; ++c4) {
    // blend: wave w handles b-hat = w*4+q; C[v][c] = sum_p w[v,p] T[b,p,c]
    f32x4 abl[4];
#pragma unroll
    for (int q = 0; q < 4; ++q) {
      const int bg = mtile * 64 + c4 * 16 + w * 4 + q;
      const bf16x8 tf = *(const bf16x8*)(tpack + (size_t)bg * 512 + l * 8);
      f32x4 z = {0.f, 0.f, 0.f, 0.f};
      abl[q] = __builtin_amdgcn_mfma_f32_16x16x32_bf16(wfrag, tf, z, 0, 0, 0);
    }
    if (lrow < 12) {
#pragma unroll
      for (int q = 0; q < 4; ++q)
#pragma unroll
        for (int r = 0; r < 4; ++r)
          Abuf[((w * 4 + q) * 16 + lk * 4 + r) * 12 + lrow] = abl[q][r];
    }
    __syncthreads();
    // apply: thread t -> (b-hat = t>>4, v = t&15)
    if (vg < Vc) {
      const int bh = t >> 4;
      const float* vp = &vposed[(c4 * 16 + bh) * 48 + (t & 15) * 3];
      const float vp0 = vp[0], vp1 = vp[1], vp2 = vp[2];
      const float* Ab = &Abuf[(bh * 16 + (t & 15)) * 12];
      float* op = out + ((size_t)(mtile * 64 + c4 * 16 + bh) * Vc + vg) * 3;
      op[0] = vp0 * Ab[0] + vp1 * Ab[3] + vp2 * Ab[6] + Ab[9];
      op[1] = vp0 * Ab[1] + vp1 * Ab[4] + vp2 * Ab[7] + Ab[10];
      op[2] = vp0 * Ab[2] + vp1 * Ab[5] + vp2 * Ab[8] + Ab[11];
    }
    __syncthreads();   // before next chunk overwrites Abuf
  }
}

extern "C" void kernel_launch(void* const* d_in, const int* in_sizes, int n_in,
                              void* d_out, int out_size, void* d_ws, size_t ws_size,
                              hipStream_t stream) {
  (void)in_sizes; (void)n_in; (void)out_size; (void)ws_size;
  const float* x      = (const float*)d_in[0];
  const float* s_mat  = (const float*)d_in[1];
  const float* v_tmpl = (const float*)d_in[2];
  const float* w_skin = (const float*)d_in[3];
  const float* j_reg  = (const float*)d_in[4];
  float* out = (float*)d_out;
  char* ws = (char*)d_ws;

  float*          js      = (float*)(ws + JS_BYTE);
  float*          coefT   = (float*)(ws + COEF_BYTE);
  float*          rotdata = (float*)(ws + ROT_BYTE);
  unsigned short* wsA     = (unsigned short*)(ws + WSA_BYTE);
  unsigned short* wsB     = (unsigned short*)(ws + WSB_BYTE);
  float*          rotR    = (float*)(ws + ROTR_BYTE);   // dead after chain2
  unsigned short* tpck    = (unsigned short*)(ws + TP_BYTE);  // aliases rotR (safe)
  unsigned short* wpck    = (unsigned short*)(ws + WP_BYTE);

  lbs_prep_kernel<<<dim3(SDc + 1, Pc), 256, 0, stream>>>(s_mat, v_tmpl, j_reg, js);
  lbs_packB48_kernel<<<(VTILES * KOCT * 48 + 255) / 256, 256, 0, stream>>>(s_mat, wsB);
  lbs_wpack_kernel<<<(VTILES * 64 + 255) / 256, 256, 0, stream>>>(w_skin, wpck);
  lbs_rodr_kernel<<<dim3(Bc / 64, NJ), 64, 0, stream>>>(x, coefT, rotR);
  lbs_chain2_kernel<<<dim3(Bc / 4), 256, 0, stream>>>(x, js, rotR, coefT, rotdata);
  lbs_packA_kernel<<<(MTILES * KOCT * 64 + 255) / 256, 256, 0, stream>>>(coefT, wsA);
  lbs_tpack_kernel<<<(Bc * 64 + 255) / 256, 256, 0, stream>>>(rotdata, tpck);
  lbs_fused_kernel<<<dim3(MTILES, VTILES), 256, 0, stream>>>(wsA, wsB, tpck, wpck, v_tmpl, out);
}

// Round 14
// 177.214 us; speedup vs baseline: 1.5283x; 1.1138x over previous
//
#include <hip/hip_runtime.h>
#include <hip/hip_bf16.h>

constexpr int Bc  = 1024;
constexpr int Vc  = 6890;
constexpr int Pc  = 24;
constexpr int SDc = 10;
constexpr int NJ  = Pc - 1;          // 23 rotated joints
constexpr int NC  = SDc + 9 * NJ;    // 217 coefficients
constexpr int V3  = 3 * Vc;          // 20670
constexpr int XD  = SDc + 3 * NJ;    // 79 input dims per batch

constexpr int KPAD   = 224;          // 217 padded to 7*32
constexpr int KOCT   = KPAD / 8;     // 28 k-octets
constexpr int MT     = 64;           // GEMM M tile (batch)
constexpr int NT     = 48;           // GEMM N tile: 16 whole vertices
constexpr int MTILES = Bc / MT;      // 16
constexpr int VTILES = (V3 + NT - 1) / NT;  // 431

// ---- workspace layout (byte offsets) ----
constexpr size_t JS_BYTE   = 0;                          // 792 f32
constexpr size_t COEF_BYTE = 4096;                       // coefT [NC][B] f32
constexpr size_t ROT_BYTE  = COEF_BYTE + 889856;         // rotdata [B][24][12] f32
constexpr size_t WSA_BYTE  = ROT_BYTE + 1179648 + 1024;  // A bf16 blocked 458752 B
constexpr size_t WSB_BYTE  = WSA_BYTE + 458752;          // B bf16 48-col blocked 9268224 B
constexpr size_t TP_BYTE   = WSB_BYTE + 9268224;         // T_pack bf16 [B][4][16][8] 1048576 B
constexpr size_t WP_BYTE   = TP_BYTE + 1048576;          // w_pack bf16 [431][4][16][8] 441344 B

typedef __attribute__((ext_vector_type(8))) short bf16x8;
typedef __attribute__((ext_vector_type(4))) float f32x4;

__device__ inline unsigned short bf16bits(float f) {
  union { float f; unsigned u; } x; x.f = f;
  unsigned r = x.u + 0x7fffu + ((x.u >> 16) & 1u);   // RNE
  return (unsigned short)(r >> 16);
}

// ---------------- Kernel A: batch-independent joint-regressor fold ----------
__global__ __launch_bounds__(256) void lbs_prep_kernel(
    const float* __restrict__ s_mat, const float* __restrict__ v_tmpl,
    const float* __restrict__ j_reg, float* __restrict__ ws) {
  const int d = blockIdx.x;            // 0..SD   (SD => v_tmpl row)
  const int p = blockIdx.y;            // 0..P-1
  const float* src = (d < SDc) ? (s_mat + (size_t)d * V3) : v_tmpl;
  const float* jr  = j_reg + (size_t)p * Vc;
  float a0 = 0.f, a1 = 0.f, a2 = 0.f;
  for (int v = threadIdx.x; v < Vc; v += 256) {
    float w = jr[v];
    a0 += w * src[3 * v + 0];
    a1 += w * src[3 * v + 1];
    a2 += w * src[3 * v + 2];
  }
  for (int off = 32; off > 0; off >>= 1) {
    a0 += __shfl_down(a0, off);
    a1 += __shfl_down(a1, off);
    a2 += __shfl_down(a2, off);
  }
  __shared__ float red[3][4];
  const int lane = threadIdx.x & 63, wid = threadIdx.x >> 6;
  if (lane == 0) { red[0][wid] = a0; red[1][wid] = a1; red[2][wid] = a2; }
  __syncthreads();
  if (threadIdx.x == 0) {
    float r0 = red[0][0] + red[0][1] + red[0][2] + red[0][3];
    float r1 = red[1][0] + red[1][1] + red[1][2] + red[1][3];
    float r2 = red[2][0] + red[2][1] + red[2][2] + red[2][3];
    float* dst = (d < SDc) ? (ws + ((size_t)d * Pc + p) * 3)
                           : (ws + 720 + (size_t)p * 3);
    dst[0] = r0; dst[1] = r1; dst[2] = r2;
  }
}

// ---------------- chain2: Rodrigues (in-wave) + kinematic scan -------------
// 4 batches/block, wave per batch. Lane i<23 computes R_i; lane p<24 computes
// J[p]; 23-step scan via shfl broadcast; lane 0 writes T; lanes write coefT.
__global__ __launch_bounds__(256) void lbs_chain2_kernel(
    const float* __restrict__ x, const float* __restrict__ ws_js,
    float* __restrict__ coefT, float* __restrict__ rotdata) {
  __shared__ float js[792];
  __shared__ float xl[4 * 80];
  const int t = threadIdx.x;
  const int b0 = blockIdx.x * 4;
  for (int i = t; i < 792; i += 256) js[i] = ws_js[i];
  for (int j = t; j < 4 * XD; j += 256) {
    const int q = j / XD, d = j - q * XD;
    xl[q * 80 + d] = x[(size_t)(b0 + q) * XD + d];
  }
  __syncthreads();

  const int wv = t >> 6, l = t & 63;
  const int b = b0 + wv;
  const float* xw = xl + wv * 80;

  // J[p] in lane p (p<24)
  float J0 = 0.f, J1 = 0.f, J2 = 0.f;
  if (l < Pc) {
    J0 = js[720 + l * 3 + 0]; J1 = js[720 + l * 3 + 1]; J2 = js[720 + l * 3 + 2];
#pragma unroll
    for (int d = 0; d < SDc; ++d) {
      const float xd = xw[d];
      J0 += xd * js[(d * Pc + l) * 3 + 0];
      J1 += xd * js[(d * Pc + l) * 3 + 1];
      J2 += xd * js[(d * Pc + l) * 3 + 2];
    }
  }
  if (l < SDc) coefT[(size_t)l * Bc + b] = xw[l];

  // Rodrigues in lane i (i<23)
  float R[9];
  {
    const int il = (l < NJ) ? l : 0;
    const float r0 = xw[SDc + 3 * il + 0], r1 = xw[SDc + 3 * il + 1], r2 = xw[SDc + 3 * il + 2];
    const float th = sqrtf(r0 * r0 + r1 * r1 + r2 * r2);
    const float inv = 1.0f / fmaxf(th, 1e-8f);
    const float n0 = r0 * inv, n1 = r1 * inv, n2 = r2 * inv;
    const float cth = cosf(th), sth = sinf(th), omc = 1.0f - cth;
    R[0] = cth + omc * n0 * n0;      R[1] = omc * n0 * n1 - sth * n2; R[2] = omc * n0 * n2 + sth * n1;
    R[3] = omc * n1 * n0 + sth * n2; R[4] = cth + omc * n1 * n1;      R[5] = omc * n1 * n2 - sth * n0;
    R[6] = omc * n2 * n0 - sth * n1; R[7] = omc * n2 * n1 + sth * n0; R[8] = cth + omc * n2 * n2;
  }
  if (l < NJ) {
#pragma unroll
    for (int q = 0; q < 9; ++q)
      coefT[(size_t)(SDc + 9 * l + q) * Bc + b] =
          R[q] - ((q == 0 || q == 4 || q == 8) ? 1.0f : 0.0f);
  }

  float rot00 = 1, rot01 = 0, rot02 = 0,
        rot10 = 0, rot11 = 1, rot12 = 0,
        rot20 = 0, rot21 = 0, rot22 = 1;
  float tr0 = __shfl(J0, 0), tr1 = __shfl(J1, 0), tr2 = __shfl(J2, 0);

  if (l < 12) rotdata[((size_t)b * Pc + 0) * 12 + l] = (l == 0 || l == 4 || l == 8) ? 1.f : 0.f;

#pragma unroll
  for (int i = 0; i < NJ; ++i) {
    const int n = i + 1;
    float Rb[9];
#pragma unroll
    for (int q = 0; q < 9; ++q) Rb[q] = __shfl(R[q], i);
    const float Jn0 = __shfl(J0, n), Jn1 = __shfl(J1, n), Jn2 = __shfl(J2, n);
    const float Ji0 = __shfl(J0, i), Ji1 = __shfl(J1, i), Ji2 = __shfl(J2, i);
    const float d0 = Jn0 - Ji0, d1 = Jn1 - Ji1, d2 = Jn2 - Ji2;
    const float ntr0 = d0 * rot00 + d1 * rot10 + d2 * rot20 + tr0;
    const float ntr1 = d0 * rot01 + d1 * rot11 + d2 * rot21 + tr1;
    const float ntr2 = d0 * rot02 + d1 * rot12 + d2 * rot22 + tr2;
    const float nr00 = Rb[0] * rot00 + Rb[3] * rot10 + Rb[6] * rot20;
    const float nr01 = Rb[0] * rot01 + Rb[3] * rot11 + Rb[6] * rot21;
    const float nr02 = Rb[0] * rot02 + Rb[3] * rot12 + Rb[6] * rot22;
    const float nr10 = Rb[1] * rot00 + Rb[4] * rot10 + Rb[7] * rot20;
    const float nr11 = Rb[1] * rot01 + Rb[4] * rot11 + Rb[7] * rot21;
    const float nr12 = Rb[1] * rot02 + Rb[4] * rot12 + Rb[7] * rot22;
    const float nr20 = Rb[2] * rot00 + Rb[5] * rot10 + Rb[8] * rot20;
    const float nr21 = Rb[2] * rot01 + Rb[5] * rot11 + Rb[8] * rot21;
    const float nr22 = Rb[2] * rot02 + Rb[5] * rot12 + Rb[8] * rot22;
    rot00 = nr00; rot01 = nr01; rot02 = nr02;
    rot10 = nr10; rot11 = nr11; rot12 = nr12;
    rot20 = nr20; rot21 = nr21; rot22 = nr22;
    tr0 = ntr0; tr1 = ntr1; tr2 = ntr2;
    const float ta0 = tr0 - (Jn0 * rot00 + Jn1 * rot10 + Jn2 * rot20);
    const float ta1 = tr1 - (Jn0 * rot01 + Jn1 * rot11 + Jn2 * rot21);
    const float ta2 = tr2 - (Jn0 * rot02 + Jn1 * rot12 + Jn2 * rot22);
    if (l == 0) {
      float* rdn = rotdata + ((size_t)b * Pc + n) * 12;
      rdn[0] = rot00; rdn[1] = rot01; rdn[2] = rot02;
      rdn[3] = rot10; rdn[4] = rot11; rdn[5] = rot12;
      rdn[6] = rot20; rdn[7] = rot21; rdn[8] = rot22;
      rdn[9] = ta0; rdn[10] = ta1; rdn[11] = ta2;
    }
  }
}

// ---------------- packB48: s_mat -> bf16 blocked [vtile][koct][48][8] -------
__global__ __launch_bounds__(256) void lbs_packB48_kernel(
    const float* __restrict__ s_mat, unsigned short* __restrict__ wsB) {
  const int idx = blockIdx.x * 256 + threadIdx.x;
  if (idx >= VTILES * KOCT * 48) return;
  const int col = idx % 48;
  const int ko  = (idx / 48) % KOCT;
  const int vt  = idx / (48 * KOCT);
  const int n = vt * 48 + col;
  unsigned short v8[8];
#pragma unroll
  for (int j = 0; j < 8; ++j) {
    const int k = ko * 8 + j;
    const float f = (k < NC && n < V3) ? s_mat[(size_t)k * V3 + n] : 0.f;
    v8[j] = bf16bits(f);
  }
  *(uint4*)&wsB[(size_t)idx * 8] = *(const uint4*)v8;
}

// ---------------- packA: coefT -> bf16 blocked [mtile][koct][64][8] ---------
__global__ __launch_bounds__(256) void lbs_packA_kernel(
    const float* __restrict__ coefT, unsigned short* __restrict__ wsA) {
  const int idx = blockIdx.x * 256 + threadIdx.x;
  if (idx >= MTILES * KOCT * 64) return;
  const int m_local = idx & 63;
  const int ko = (idx >> 6) % KOCT;
  const int mtile = idx / (64 * KOCT);
  const int b = mtile * 64 + m_local;
  unsigned short v8[8];
#pragma unroll
  for (int j = 0; j < 8; ++j) {
    const int k = ko * 8 + j;
    const float f = (k < NC) ? coefT[(size_t)k * Bc + b] : 0.f;
    v8[j] = bf16bits(f);
  }
  *(uint4*)&wsA[(size_t)idx * 8] = *(const uint4*)v8;
}

// ---------------- tpack: rotdata -> bf16 B-operand layout [b][ko4][c16][j8] -
__global__ __launch_bounds__(256) void lbs_tpack_kernel(
    const float* __restrict__ rotdata, unsigned short* __restrict__ tp) {
  const int idx = blockIdx.x * 256 + threadIdx.x;
  if (idx >= Bc * 4 * 16) return;
  const int c  = idx & 15;
  const int ko = (idx >> 4) & 3;
  const int b  = idx >> 6;
  unsigned short v8[8];
#pragma unroll
  for (int j = 0; j < 8; ++j) {
    const int p = ko * 8 + j;
    const float f = (p < Pc && c < 12) ? rotdata[((size_t)b * Pc + p) * 12 + c] : 0.f;
    v8[j] = bf16bits(f);
  }
  *(uint4*)&tp[(size_t)idx * 8] = *(const uint4*)v8;
}

// ---------------- wpack: w_skin -> bf16 A-operand layout [vt][ko4][v16][j8] -
__global__ __launch_bounds__(256) void lbs_wpack_kernel(
    const float* __restrict__ w_skin, unsigned short* __restrict__ wp) {
  const int idx = blockIdx.x * 256 + threadIdx.x;
  if (idx >= VTILES * 4 * 16) return;
  const int i  = idx & 15;
  const int ko = (idx >> 4) & 3;
  const int vt = idx >> 6;
  const int v = vt * 16 + i;
  unsigned short v8[8];
#pragma unroll
  for (int j = 0; j < 8; ++j) {
    const int p = ko * 8 + j;
    const float f = (p < Pc && v < Vc) ? w_skin[(size_t)v * Pc + p] : 0.f;
    v8[j] = bf16bits(f);
  }
  *(uint4*)&wp[(size_t)idx * 8] = *(const uint4*)v8;
}

// ---------------- fused: blendshape-GEMM + MFMA skinning -> out -------------
// A-fragments from global (wave-private rows; 4x256B coalesced) -> LDS only
// for B (21.5KB) reused as vposed[64][50] + Abuf[256][13] (26.1KB) in phase 2.
// Pads: 50 (4*50%32=8 -> uniform 2-way, free) / 13 (coprime 32).
__global__ __launch_bounds__(256) void lbs_fused_kernel(
    const unsigned short* __restrict__ wsA, const unsigned short* __restrict__ wsB,
    const unsigned short* __restrict__ tpack, const unsigned short* __restrict__ wpack,
    const float* __restrict__ v_tmpl, float* __restrict__ out) {
  __shared__ __align__(16) unsigned char lds[26112];
  unsigned short* lB = (unsigned short*)lds;                    // [ko][48][8] 21504 B
  float* vposed = (float*)lds;                                  // [64][50] 12800 B
  float* Abuf   = (float*)(lds + 12800);                        // [16b*16v][13] 13312 B

  const int mtile = blockIdx.x;
  const int vt    = blockIdx.y;
  const int t = threadIdx.x;
  const int w = t >> 6, l = t & 63;
  const int lrow = l & 15, lk = l >> 4;

  // ---- stage B tile ----
  const unsigned short* gB = wsB + (size_t)vt * (KOCT * 48 * 8);
#pragma unroll
  for (int i = 0; i < 6; ++i) {
    const int idx = t + i * 256;
    if (idx < 1344) ((uint4*)lB)[idx] = ((const uint4*)gB)[idx];
  }
  __syncthreads();

  // ---- phase 1: wave w owns m-rows [w*16, w*16+16); A from global ----
  const unsigned short* gA = wsA + (size_t)mtile * (KPAD * MT);
  f32x4 acc[3] = {};
#pragma unroll
  for (int kk = 0; kk < 7; ++kk) {
    const int ko = kk * 4 + lk;
    const bf16x8 a = *(const bf16x8*)&gA[(ko * 64 + w * 16 + lrow) * 8];
#pragma unroll
    for (int f = 0; f < 3; ++f) {
      const bf16x8 bf = *(const bf16x8*)&lB[(ko * 48 + f * 16 + lrow) * 8];
      acc[f] = __builtin_amdgcn_mfma_f32_16x16x32_bf16(a, bf, acc[f], 0, 0, 0);
    }
  }

  const bf16x8 wfrag = *(const bf16x8*)(wpack + (size_t)vt * 512 + l * 8);

  __syncthreads();   // done reading lB; reuse LDS

  // ---- v_posed (+v_tmpl) -> LDS [m 64][col 48 pad 50]
#pragma unroll
  for (int f = 0; f < 3; ++f) {
    const int ng = vt * 48 + f * 16 + lrow;
    const float vtv = (ng < V3) ? v_tmpl[ng] : 0.f;
#pragma unroll
    for (int r = 0; r < 4; ++r)
      vposed[(w * 16 + lk * 4 + r) * 50 + f * 16 + lrow] = acc[f][r] + vtv;
  }
  __syncthreads();

  // ---- phase 2: 4 chunks of 16 batches
  const int vg = vt * 16 + (t & 15);
  for (int c4 = 0; c4 < 4; ++c4) {
    f32x4 abl[4];
#pragma unroll
    for (int q = 0; q < 4; ++q) {
      const int bg = mtile * 64 + c4 * 16 + w * 4 + q;
      const bf16x8 tf = *(const bf16x8*)(tpack + (size_t)bg * 512 + l * 8);
      f32x4 z = {0.f, 0.f, 0.f, 0.f};
      abl[q] = __builtin_amdgcn_mfma_f32_16x16x32_bf16(wfrag, tf, z, 0, 0, 0);
    }
    if (lrow < 12) {
#pragma unroll
      for (int q = 0; q < 4; ++q)
#pragma unroll
        for (int r = 0; r < 4; ++r)
          Abuf[((w * 4 + q) * 16 + lk * 4 + r) * 13 + lrow] = abl[q][r];
    }
    __syncthreads();
    if (vg < Vc) {
      const int bh = t >> 4;
      const float* vp = &vposed[(c4 * 16 + bh) * 50 + (t & 15) * 3];
      const float vp0 = vp[0], vp1 = vp[1], vp2 = vp[2];
      const float* Ab = &Abuf[(bh * 16 + (t & 15)) * 13];
      float* op = out + ((size_t)(mtile * 64 + c4 * 16 + bh) * Vc + vg) * 3;
      op[0] = vp0 * Ab[0] + vp1 * Ab[3] + vp2 * Ab[6] + Ab[9];
      op[1] = vp0 * Ab[1] + vp1 * Ab[4] + vp2 * Ab[7] + Ab[10];
      op[2] = vp0 * Ab[2] + vp1 * Ab[5] + vp2 * Ab[8] + Ab[11];
    }
    __syncthreads();
  }
}

extern "C" void kernel_launch(void* const* d_in, const int* in_sizes, int n_in,
                              void* d_out, int out_size, void* d_ws, size_t ws_size,
                              hipStream_t stream) {
  (void)in_sizes; (void)n_in; (void)out_size; (void)ws_size;
  const float* x      = (const float*)d_in[0];
  const float* s_mat  = (const float*)d_in[1];
  const float* v_tmpl = (const float*)d_in[2];
  const float* w_skin = (const float*)d_in[3];
  const float* j_reg  = (const float*)d_in[4];
  float* out = (float*)d_out;
  char* ws = (char*)d_ws;

  float*          js      = (float*)(ws + JS_BYTE);
  float*          coefT   = (float*)(ws + COEF_BYTE);
  float*          rotdata = (float*)(ws + ROT_BYTE);
  unsigned short* wsA     = (unsigned short*)(ws + WSA_BYTE);
  unsigned short* wsB     = (unsigned short*)(ws + WSB_BYTE);
  unsigned short* tpck    = (unsigned short*)(ws + TP_BYTE);
  unsigned short* wpck    = (unsigned short*)(ws + WP_BYTE);

  lbs_prep_kernel<<<dim3(SDc + 1, Pc), 256, 0, stream>>>(s_mat, v_tmpl, j_reg, js);
  lbs_packB48_kernel<<<(VTILES * KOCT * 48 + 255) / 256, 256, 0, stream>>>(s_mat, wsB);
  lbs_wpack_kernel<<<(VTILES * 64 + 255) / 256, 256, 0, stream>>>(w_skin, wpck);
  lbs_chain2_kernel<<<dim3(Bc / 4), 256, 0, stream>>>(x, js, coefT, rotdata);
  lbs_packA_kernel<<<(MTILES * KOCT * 64 + 255) / 256, 256, 0, stream>>>(coefT, wsA);
  lbs_tpack_kernel<<<(Bc * 64 + 255) / 256, 256, 0, stream>>>(rotdata, tpck);
  lbs_fused_kernel<<<dim3(MTILES, VTILES), 256, 0, stream>>>(wsA, wsB, tpck, wpck, v_tmpl, out);
}

// Round 15
// 170.501 us; speedup vs baseline: 1.5885x; 1.0394x over previous
//
#include <hip/hip_runtime.h>
#include <hip/hip_bf16.h>

constexpr int Bc  = 1024;
constexpr int Vc  = 6890;
constexpr int Pc  = 24;
constexpr int SDc = 10;
constexpr int NJ  = Pc - 1;          // 23 rotated joints
constexpr int NC  = SDc + 9 * NJ;    // 217 coefficients
constexpr int V3  = 3 * Vc;          // 20670
constexpr int XD  = SDc + 3 * NJ;    // 79 input dims per batch

constexpr int KPAD   = 224;          // 217 padded to 7*32
constexpr int KOCT   = KPAD / 8;     // 28 k-octets
constexpr int MT     = 64;           // GEMM M tile (batch)
constexpr int NT     = 48;           // GEMM N tile: 16 whole vertices
constexpr int MTILES = Bc / MT;      // 16
constexpr int VTILES = (V3 + NT - 1) / NT;  // 431

// static_prep role split
constexpr int PB_BLOCKS   = (VTILES * KOCT * 48 + 255) / 256;  // 2263
constexpr int WPK_BLOCKS  = (VTILES * 64 + 255) / 256;         // 108
constexpr int PREP_BLOCKS = (SDc + 1) * Pc;                    // 264

// ---- workspace layout (byte offsets) ----
constexpr size_t JS_BYTE  = 0;                          // 792 f32
constexpr size_t WSA_BYTE = 4096;                       // A bf16 blocked 458752 B
constexpr size_t WSB_BYTE = WSA_BYTE + 458752;          // B bf16 48-col blocked 9268224 B
constexpr size_t TP_BYTE  = WSB_BYTE + 9268224;         // T_pack bf16 [B][4][16][8] 1048576 B
constexpr size_t WP_BYTE  = TP_BYTE + 1048576;          // w_pack bf16 [431][4][16][8] 441344 B

typedef __attribute__((ext_vector_type(8))) short bf16x8;
typedef __attribute__((ext_vector_type(4))) float f32x4;

__device__ inline unsigned short bf16bits(float f) {
  union { float f; unsigned u; } x; x.f = f;
  unsigned r = x.u + 0x7fffu + ((x.u >> 16) & 1u);   // RNE
  return (unsigned short)(r >> 16);
}

// ---------------- static_prep: packB48 + wpack + prep in ONE launch ---------
__global__ __launch_bounds__(256) void lbs_static_prep_kernel(
    const float* __restrict__ s_mat, const float* __restrict__ v_tmpl,
    const float* __restrict__ j_reg, const float* __restrict__ w_skin,
    unsigned short* __restrict__ wsB, unsigned short* __restrict__ wp,
    float* __restrict__ js_out) {
  const int bid = blockIdx.x;
  const int tid = threadIdx.x;

  if (bid < PB_BLOCKS) {
    // ---- packB48: s_mat -> bf16 blocked [vtile][koct][48][8]
    const int idx = bid * 256 + tid;
    if (idx < VTILES * KOCT * 48) {
      const int col = idx % 48;
      const int ko  = (idx / 48) % KOCT;
      const int vt  = idx / (48 * KOCT);
      const int n = vt * 48 + col;
      unsigned short v8[8];
#pragma unroll
      for (int j = 0; j < 8; ++j) {
        const int k = ko * 8 + j;
        const float f = (k < NC && n < V3) ? s_mat[(size_t)k * V3 + n] : 0.f;
        v8[j] = bf16bits(f);
      }
      *(uint4*)&wsB[(size_t)idx * 8] = *(const uint4*)v8;
    }
    return;
  }
  if (bid < PB_BLOCKS + WPK_BLOCKS) {
    // ---- wpack: w_skin -> bf16 A-operand layout [vt][ko4][v16][j8]
    const int idx = (bid - PB_BLOCKS) * 256 + tid;
    if (idx < VTILES * 64) {
      const int i  = idx & 15;
      const int ko = (idx >> 4) & 3;
      const int vt = idx >> 6;
      const int v = vt * 16 + i;
      unsigned short v8[8];
#pragma unroll
      for (int j = 0; j < 8; ++j) {
        const int p = ko * 8 + j;
        const float f = (p < Pc && v < Vc) ? w_skin[(size_t)v * Pc + p] : 0.f;
        v8[j] = bf16bits(f);
      }
      *(uint4*)&wp[(size_t)idx * 8] = *(const uint4*)v8;
    }
    return;
  }
  // ---- prep: joint-regressor fold (JS table)
  {
    const int r = bid - PB_BLOCKS - WPK_BLOCKS;   // 0..263
    const int d = r / Pc;                          // 0..SD
    const int p = r % Pc;
    const float* src = (d < SDc) ? (s_mat + (size_t)d * V3) : v_tmpl;
    const float* jr  = j_reg + (size_t)p * Vc;
    float a0 = 0.f, a1 = 0.f, a2 = 0.f;
    for (int v = tid; v < Vc; v += 256) {
      float w = jr[v];
      a0 += w * src[3 * v + 0];
      a1 += w * src[3 * v + 1];
      a2 += w * src[3 * v + 2];
    }
    for (int off = 32; off > 0; off >>= 1) {
      a0 += __shfl_down(a0, off);
      a1 += __shfl_down(a1, off);
      a2 += __shfl_down(a2, off);
    }
    __shared__ float red[3][4];
    const int lane = tid & 63, wid = tid >> 6;
    if (lane == 0) { red[0][wid] = a0; red[1][wid] = a1; red[2][wid] = a2; }
    __syncthreads();
    if (tid == 0) {
      float r0 = red[0][0] + red[0][1] + red[0][2] + red[0][3];
      float r1 = red[1][0] + red[1][1] + red[1][2] + red[1][3];
      float r2 = red[2][0] + red[2][1] + red[2][2] + red[2][3];
      float* dst = (d < SDc) ? (js_out + ((size_t)d * Pc + p) * 3)
                             : (js_out + 720 + (size_t)p * 3);
      dst[0] = r0; dst[1] = r1; dst[2] = r2;
    }
  }
}

// ---------------- chain2: Rodrigues + scan + DIRECT bf16 packing -----------
// 4 batches/block, wave per batch. Lane i<23: Rodrigues R_i. Lane p<24: J[p].
// 23-step scan via shfl (all lanes redundant); lane n snapshots T_n.
// Emits wsA (A-operand octets) and tp (T-operand octets) directly — no
// coefT/rotdata global round-trips, no packA/tpack kernels.
__global__ __launch_bounds__(256) void lbs_chain2_kernel(
    const float* __restrict__ x, const float* __restrict__ ws_js,
    unsigned short* __restrict__ wsA, unsigned short* __restrict__ tp) {
  __shared__ float js[792];
  __shared__ float xl[4][80];
  __shared__ float cl[4][207];      // R - I coefs (k=10..216) per wave
  __shared__ float Tl[4][24][12];   // T per wave
  const int t = threadIdx.x;
  const int b0 = blockIdx.x * 4;
  for (int i = t; i < 792; i += 256) js[i] = ws_js[i];
  for (int j = t; j < 4 * XD; j += 256) {
    const int q = j / XD, d = j - q * XD;
    xl[q][d] = x[(size_t)(b0 + q) * XD + d];
  }
  __syncthreads();

  const int wv = t >> 6, l = t & 63;
  const int b = b0 + wv;
  const float* xw = xl[wv];

  // J[p] in lane p (p<24)
  float J0 = 0.f, J1 = 0.f, J2 = 0.f;
  if (l < Pc) {
    J0 = js[720 + l * 3 + 0]; J1 = js[720 + l * 3 + 1]; J2 = js[720 + l * 3 + 2];
#pragma unroll
    for (int d = 0; d < SDc; ++d) {
      const float xd = xw[d];
      J0 += xd * js[(d * Pc + l) * 3 + 0];
      J1 += xd * js[(d * Pc + l) * 3 + 1];
      J2 += xd * js[(d * Pc + l) * 3 + 2];
    }
  }

  // Rodrigues in lane i (i<23)
  float R[9];
  {
    const int il = (l < NJ) ? l : 0;
    const float r0 = xw[SDc + 3 * il + 0], r1 = xw[SDc + 3 * il + 1], r2 = xw[SDc + 3 * il + 2];
    const float th = sqrtf(r0 * r0 + r1 * r1 + r2 * r2);
    const float inv = 1.0f / fmaxf(th, 1e-8f);
    const float n0 = r0 * inv, n1 = r1 * inv, n2 = r2 * inv;
    const float cth = cosf(th), sth = sinf(th), omc = 1.0f - cth;
    R[0] = cth + omc * n0 * n0;      R[1] = omc * n0 * n1 - sth * n2; R[2] = omc * n0 * n2 + sth * n1;
    R[3] = omc * n1 * n0 + sth * n2; R[4] = cth + omc * n1 * n1;      R[5] = omc * n1 * n2 - sth * n0;
    R[6] = omc * n2 * n0 - sth * n1; R[7] = omc * n2 * n1 + sth * n0; R[8] = cth + omc * n2 * n2;
  }

  float Treg[12] = {0, 0, 0, 0, 0, 0, 0, 0, 0, 0, 0, 0};
  if (l == 0) { Treg[0] = 1; Treg[4] = 1; Treg[8] = 1; }   // node 0: I, ta=0

  float rot00 = 1, rot01 = 0, rot02 = 0,
        rot10 = 0, rot11 = 1, rot12 = 0,
        rot20 = 0, rot21 = 0, rot22 = 1;
  float tr0 = __shfl(J0, 0), tr1 = __shfl(J1, 0), tr2 = __shfl(J2, 0);

#pragma unroll
  for (int i = 0; i < NJ; ++i) {
    const int n = i + 1;
    float Rb[9];
#pragma unroll
    for (int q = 0; q < 9; ++q) Rb[q] = __shfl(R[q], i);
    const float Jn0 = __shfl(J0, n), Jn1 = __shfl(J1, n), Jn2 = __shfl(J2, n);
    const float Ji0 = __shfl(J0, i), Ji1 = __shfl(J1, i), Ji2 = __shfl(J2, i);
    const float d0 = Jn0 - Ji0, d1 = Jn1 - Ji1, d2 = Jn2 - Ji2;
    const float ntr0 = d0 * rot00 + d1 * rot10 + d2 * rot20 + tr0;
    const float ntr1 = d0 * rot01 + d1 * rot11 + d2 * rot21 + tr1;
    const float ntr2 = d0 * rot02 + d1 * rot12 + d2 * rot22 + tr2;
    const float nr00 = Rb[0] * rot00 + Rb[3] * rot10 + Rb[6] * rot20;
    const float nr01 = Rb[0] * rot01 + Rb[3] * rot11 + Rb[6] * rot21;
    const float nr02 = Rb[0] * rot02 + Rb[3] * rot12 + Rb[6] * rot22;
    const float nr10 = Rb[1] * rot00 + Rb[4] * rot10 + Rb[7] * rot20;
    const float nr11 = Rb[1] * rot01 + Rb[4] * rot11 + Rb[7] * rot21;
    const float nr12 = Rb[1] * rot02 + Rb[4] * rot12 + Rb[7] * rot22;
    const float nr20 = Rb[2] * rot00 + Rb[5] * rot10 + Rb[8] * rot20;
    const float nr21 = Rb[2] * rot01 + Rb[5] * rot11 + Rb[8] * rot21;
    const float nr22 = Rb[2] * rot02 + Rb[5] * rot12 + Rb[8] * rot22;
    rot00 = nr00; rot01 = nr01; rot02 = nr02;
    rot10 = nr10; rot11 = nr11; rot12 = nr12;
    rot20 = nr20; rot21 = nr21; rot22 = nr22;
    tr0 = ntr0; tr1 = ntr1; tr2 = ntr2;
    const float ta0 = tr0 - (Jn0 * rot00 + Jn1 * rot10 + Jn2 * rot20);
    const float ta1 = tr1 - (Jn0 * rot01 + Jn1 * rot11 + Jn2 * rot21);
    const float ta2 = tr2 - (Jn0 * rot02 + Jn1 * rot12 + Jn2 * rot22);
    if (l == n) {
      Treg[0] = rot00; Treg[1] = rot01; Treg[2] = rot02;
      Treg[3] = rot10; Treg[4] = rot11; Treg[5] = rot12;
      Treg[6] = rot20; Treg[7] = rot21; Treg[8] = rot22;
      Treg[9] = ta0; Treg[10] = ta1; Treg[11] = ta2;
    }
  }

  // stage pack sources in LDS
  if (l < NJ) {
#pragma unroll
    for (int q = 0; q < 9; ++q)
      cl[wv][9 * l + q] = R[q] - ((q == 0 || q == 4 || q == 8) ? 1.0f : 0.0f);
  }
  if (l < Pc) {
#pragma unroll
    for (int c = 0; c < 12; ++c) Tl[wv][l][c] = Treg[c];
  }
  __syncthreads();

  const int mtile = b >> 6, m_local = b & 63;
  // pack A octets: lane l < 28 handles k = 8l..8l+7
  if (l < KOCT) {
    unsigned short v8[8];
#pragma unroll
    for (int j = 0; j < 8; ++j) {
      const int k = l * 8 + j;
      const float f = (k < SDc) ? xw[k] : ((k < NC) ? cl[wv][k - SDc] : 0.f);
      v8[j] = bf16bits(f);
    }
    *(uint4*)&wsA[(size_t)((mtile * KOCT + l) * 64 + m_local) * 8] = *(const uint4*)v8;
  }
  // pack T octets: lane l -> (ko = l>>4, c = l&15)
  {
    const int ko = l >> 4, c = l & 15;
    unsigned short v8[8];
#pragma unroll
    for (int j = 0; j < 8; ++j) {
      const int p = ko * 8 + j;
      const float f = (p < Pc && c < 12) ? Tl[wv][p][c] : 0.f;
      v8[j] = bf16bits(f);
    }
    *(uint4*)&tp[(size_t)(b * 64 + l) * 8] = *(const uint4*)v8;
  }
}

// ---------------- fused: blendshape-GEMM + MFMA skinning -> out -------------
// A-fragments from global (wave-private rows; coalesced) -> LDS only for B
// (21.5KB) reused as vposed[64][50] + Abuf[256][13] in phase 2.
__global__ __launch_bounds__(256) void lbs_fused_kernel(
    const unsigned short* __restrict__ wsA, const unsigned short* __restrict__ wsB,
    const unsigned short* __restrict__ tpack, const unsigned short* __restrict__ wpack,
    const float* __restrict__ v_tmpl, float* __restrict__ out) {
  __shared__ __align__(16) unsigned char lds[26112];
  unsigned short* lB = (unsigned short*)lds;                    // [ko][48][8] 21504 B
  float* vposed = (float*)lds;                                  // [64][50] 12800 B
  float* Abuf   = (float*)(lds + 12800);                        // [16b*16v][13] 13312 B

  const int mtile = blockIdx.x;
  const int vt    = blockIdx.y;
  const int t = threadIdx.x;
  const int w = t >> 6, l = t & 63;
  const int lrow = l & 15, lk = l >> 4;

  // ---- stage B tile ----
  const unsigned short* gB = wsB + (size_t)vt * (KOCT * 48 * 8);
#pragma unroll
  for (int i = 0; i < 6; ++i) {
    const int idx = t + i * 256;
    if (idx < 1344) ((uint4*)lB)[idx] = ((const uint4*)gB)[idx];
  }
  __syncthreads();

  // ---- phase 1: wave w owns m-rows [w*16, w*16+16); A from global ----
  const unsigned short* gA = wsA + (size_t)mtile * (KPAD * MT);
  f32x4 acc[3] = {};
#pragma unroll
  for (int kk = 0; kk < 7; ++kk) {
    const int ko = kk * 4 + lk;
    const bf16x8 a = *(const bf16x8*)&gA[(ko * 64 + w * 16 + lrow) * 8];
#pragma unroll
    for (int f = 0; f < 3; ++f) {
      const bf16x8 bf = *(const bf16x8*)&lB[(ko * 48 + f * 16 + lrow) * 8];
      acc[f] = __builtin_amdgcn_mfma_f32_16x16x32_bf16(a, bf, acc[f], 0, 0, 0);
    }
  }

  const bf16x8 wfrag = *(const bf16x8*)(wpack + (size_t)vt * 512 + l * 8);

  __syncthreads();   // done reading lB; reuse LDS

  // ---- v_posed (+v_tmpl) -> LDS [m 64][col 48 pad 50]
#pragma unroll
  for (int f = 0; f < 3; ++f) {
    const int ng = vt * 48 + f * 16 + lrow;
    const float vtv = (ng < V3) ? v_tmpl[ng] : 0.f;
#pragma unroll
    for (int r = 0; r < 4; ++r)
      vposed[(w * 16 + lk * 4 + r) * 50 + f * 16 + lrow] = acc[f][r] + vtv;
  }
  __syncthreads();

  // ---- phase 2: 4 chunks of 16 batches
  const int vg = vt * 16 + (t & 15);
  for (int c4 = 0; c4 < 4; ++c4) {
    f32x4 abl[4];
#pragma unroll
    for (int q = 0; q < 4; ++q) {
      const int bg = mtile * 64 + c4 * 16 + w * 4 + q;
      const bf16x8 tf = *(const bf16x8*)(tpack + (size_t)bg * 512 + l * 8);
      f32x4 z = {0.f, 0.f, 0.f, 0.f};
      abl[q] = __builtin_amdgcn_mfma_f32_16x16x32_bf16(wfrag, tf, z, 0, 0, 0);
    }
    if (lrow < 12) {
#pragma unroll
      for (int q = 0; q < 4; ++q)
#pragma unroll
        for (int r = 0; r < 4; ++r)
          Abuf[((w * 4 + q) * 16 + lk * 4 + r) * 13 + lrow] = abl[q][r];
    }
    __syncthreads();
    if (vg < Vc) {
      const int bh = t >> 4;
      const float* vp = &vposed[(c4 * 16 + bh) * 50 + (t & 15) * 3];
      const float vp0 = vp[0], vp1 = vp[1], vp2 = vp[2];
      const float* Ab = &Abuf[(bh * 16 + (t & 15)) * 13];
      float* op = out + ((size_t)(mtile * 64 + c4 * 16 + bh) * Vc + vg) * 3;
      op[0] = vp0 * Ab[0] + vp1 * Ab[3] + vp2 * Ab[6] + Ab[9];
      op[1] = vp0 * Ab[1] + vp1 * Ab[4] + vp2 * Ab[7] + Ab[10];
      op[2] = vp0 * Ab[2] + vp1 * Ab[5] + vp2 * Ab[8] + Ab[11];
    }
    __syncthreads();
  }
}

extern "C" void kernel_launch(void* const* d_in, const int* in_sizes, int n_in,
                              void* d_out, int out_size, void* d_ws, size_t ws_size,
                              hipStream_t stream) {
  (void)in_sizes; (void)n_in; (void)out_size; (void)ws_size;
  const float* x      = (const float*)d_in[0];
  const float* s_mat  = (const float*)d_in[1];
  const float* v_tmpl = (const float*)d_in[2];
  const float* w_skin = (const float*)d_in[3];
  const float* j_reg  = (const float*)d_in[4];
  float* out = (float*)d_out;
  char* ws = (char*)d_ws;

  float*          js   = (float*)(ws + JS_BYTE);
  unsigned short* wsA  = (unsigned short*)(ws + WSA_BYTE);
  unsigned short* wsB  = (unsigned short*)(ws + WSB_BYTE);
  unsigned short* tpck = (unsigned short*)(ws + TP_BYTE);
  unsigned short* wpck = (unsigned short*)(ws + WP_BYTE);

  lbs_static_prep_kernel<<<PB_BLOCKS + WPK_BLOCKS + PREP_BLOCKS, 256, 0, stream>>>(
      s_mat, v_tmpl, j_reg, w_skin, wsB, wpck, js);
  lbs_chain2_kernel<<<dim3(Bc / 4), 256, 0, stream>>>(x, js, wsA, tpck);
  lbs_fused_kernel<<<dim3(MTILES, VTILES), 256, 0, stream>>>(wsA, wsB, tpck, wpck, v_tmpl, out);
}